// Round 1
// baseline (9615.151 us; speedup 1.0000x reference)
//
#include <hip/hip_runtime.h>
#include <hip/hip_bf16.h>
#include <math.h>

// ---------------------------------------------------------------------------
// DDRSA ProbSparse forward, fp32 reference-faithful implementation.
// Structure: embed+posenc -> enc layer1 (L=2048,u=40) -> conv distill ->
// enc layer2 (L=1024,u=35) -> mean -> LSTM(100) -> dot(out_w).
// ---------------------------------------------------------------------------

static constexpr int BATCH = 8;
static constexpr int LL1 = 2048;
static constexpr int LL2 = 1024;
static constexpr int DMODEL = 512;
static constexpr int NHEADS = 8;
static constexpr int DKH = 64;
static constexpr int TPRED = 100;

__device__ __forceinline__ float sigm(float x) { return 1.0f / (1.0f + expf(-x)); }

// ---------------- embedding + positional encoding --------------------------
__global__ void k_embed(const float* __restrict__ x, const float* __restrict__ ew,
                        const float* __restrict__ eb, float* __restrict__ out) {
  int row = blockIdx.x;            // b*2048 + l
  int l = row & (LL1 - 1);
  int tid = threadIdx.x;           // 256
  __shared__ float xr[64];
  if (tid < 64) xr[tid] = x[row * 64 + tid];
  __syncthreads();
  const float fac = -9.210340371976184f / 512.0f;   // -ln(10000)/d
  for (int c = tid; c < DMODEL; c += 256) {
    float acc = eb[c];
#pragma unroll 8
    for (int i = 0; i < 64; i++) acc = fmaf(xr[i], ew[i * DMODEL + c], acc);
    float divv = expf((float)(2 * (c >> 1)) * fac);
    float ang = (float)l * divv;
    acc += (c & 1) ? cosf(ang) : sinf(ang);
    out[row * DMODEL + c] = acc;
  }
}

// ---------------- generic tiled GEMM: C = A@W + bias, epilogues ------------
// EPI: 0 = bias, 1 = bias+GELU(exact), 2 = bias+BatchNorm+ELU (conv path)
// CONV: A rows gathered with wrap shift per 512-column block (conv1d k=3)
template <int EPI, int CONV>
__global__ __launch_bounds__(256) void k_gemm(
    const float* __restrict__ A, const float* __restrict__ W,
    const float* __restrict__ bias, float* __restrict__ C,
    int M, int N, int K, int Lc,
    const float* __restrict__ p_m, const float* __restrict__ p_v,
    const float* __restrict__ p_g, const float* __restrict__ p_b) {
  __shared__ float As[8][132];
  __shared__ float Bs[8][128];
  int tid = threadIdx.x;
  int m0 = blockIdx.y * 128, n0 = blockIdx.x * 128;
  int tx = tid & 15, ty = tid >> 4;
  float acc[8][8] = {};
  int ar = tid >> 1, ac = (tid & 1) * 4;       // A tile: 128 rows x 8 cols
  int br = tid >> 5, bc = (tid & 31) * 4;      // B tile: 8 rows x 128 cols

  for (int k0 = 0; k0 < K; k0 += 8) {
    float4 av;
    if (CONV) {
      int m = m0 + ar;
      int b = m / Lc, t = m - b * Lc;
      int kblk = (k0 + ac) >> 9;               // 0,1,2 (shift -1,0,+1)
      int srcrow = b * Lc + ((t + kblk - 1 + Lc) % Lc);
      int col = k0 + ac - (kblk << 9);
      av = *reinterpret_cast<const float4*>(&A[srcrow * DMODEL + col]);
    } else {
      av = *reinterpret_cast<const float4*>(&A[(m0 + ar) * K + k0 + ac]);
    }
    float4 bv = *reinterpret_cast<const float4*>(&W[(k0 + br) * N + n0 + bc]);
    As[ac + 0][ar] = av.x; As[ac + 1][ar] = av.y;
    As[ac + 2][ar] = av.z; As[ac + 3][ar] = av.w;
    *reinterpret_cast<float4*>(&Bs[br][bc]) = bv;
    __syncthreads();
#pragma unroll
    for (int kk = 0; kk < 8; kk++) {
      float a[8], bb[8];
#pragma unroll
      for (int i = 0; i < 8; i++) a[i] = As[kk][ty * 8 + i];
#pragma unroll
      for (int j = 0; j < 8; j++) bb[j] = Bs[kk][tx * 8 + j];
#pragma unroll
      for (int i = 0; i < 8; i++)
#pragma unroll
        for (int j = 0; j < 8; j++) acc[i][j] = fmaf(a[i], bb[j], acc[i][j]);
    }
    __syncthreads();
  }
#pragma unroll
  for (int i = 0; i < 8; i++) {
    int m = m0 + ty * 8 + i;
    float v[8];
#pragma unroll
    for (int j = 0; j < 8; j++) {
      int n = n0 + tx * 8 + j;
      float t = acc[i][j] + bias[n];
      if (EPI == 1) {
        t = 0.5f * t * (1.0f + erff(t * 0.7071067811865475f));
      } else if (EPI == 2) {
        t = (t - p_m[n]) * rsqrtf(p_v[n] + 1e-5f) * p_g[n] + p_b[n];
        t = t > 0.0f ? t : expm1f(t);
      }
      v[j] = t;
    }
    float4 o0 = {v[0], v[1], v[2], v[3]}, o1 = {v[4], v[5], v[6], v[7]};
    *reinterpret_cast<float4*>(&C[m * N + n0 + tx * 8]) = o0;
    *reinterpret_cast<float4*>(&C[m * N + n0 + tx * 8 + 4]) = o1;
  }
}

// ---------------- sampled qk -> sparsity measure M -------------------------
__global__ void k_qk_m(const float* __restrict__ Q, const float* __restrict__ Km,
                       const int* __restrict__ idx, float* __restrict__ Mout,
                       int Lc, int u) {
  int row = blockIdx.x;            // b*Lc + l
  int b = row / Lc, l = row - b * Lc;
  int tid = threadIdx.x;
  int nt = blockDim.x;
  __shared__ __align__(16) float qlds[DMODEL];
  __shared__ int ilds[40];
  __shared__ float qk[320];
  for (int i = tid; i < DMODEL; i += nt) qlds[i] = Q[row * DMODEL + i];
  for (int i = tid; i < u; i += nt) ilds[i] = idx[l * u + i];
  __syncthreads();
  int tot = NHEADS * u;
  if (tid < tot) {
    int j = tid >> 3, h = tid & 7;
    int key = ilds[j];
    const float4* kp = reinterpret_cast<const float4*>(&Km[(b * Lc + key) * DMODEL + h * DKH]);
    const float4* qp = reinterpret_cast<const float4*>(&qlds[h * DKH]);
    float s = 0.f;
#pragma unroll
    for (int d = 0; d < 16; d++) {
      float4 kv = kp[d], qv = qp[d];
      s += qv.x * kv.x + qv.y * kv.y + qv.z * kv.z + qv.w * kv.w;
    }
    qk[tid] = s;
  }
  __syncthreads();
  if (tid < NHEADS) {
    int h = tid;
    float mx = -INFINITY, sm = 0.f;
    for (int j = 0; j < u; j++) {
      float v = qk[(j << 3) + h];
      mx = fmaxf(mx, v);
      sm += v;
    }
    Mout[(b * NHEADS + h) * Lc + l] = mx - sm / (float)Lc;
  }
}

// ---------------- top-u of M per (b,h), lax.top_k tie-break ----------------
__global__ void k_topk(const float* __restrict__ Mv, int* __restrict__ mtop,
                       int Lc, int u) {
  int bh = blockIdx.x;             // 64 blocks
  int tid = threadIdx.x;           // 256
  __shared__ float vals[2048];
  __shared__ float rv[256];
  __shared__ int ri[256];
  for (int i = tid; i < Lc; i += 256) vals[i] = Mv[bh * Lc + i];
  __syncthreads();
  for (int it = 0; it < u; it++) {
    float bvv = -INFINITY; int bii = 0x7fffffff;
    for (int i = tid; i < Lc; i += 256) {
      float v = vals[i];
      if (v > bvv) { bvv = v; bii = i; }
    }
    rv[tid] = bvv; ri[tid] = bii;
    __syncthreads();
    for (int s = 128; s > 0; s >>= 1) {
      if (tid < s) {
        float v2 = rv[tid + s]; int i2 = ri[tid + s];
        if (v2 > rv[tid] || (v2 == rv[tid] && i2 < ri[tid])) { rv[tid] = v2; ri[tid] = i2; }
      }
      __syncthreads();
    }
    if (tid == 0) { mtop[bh * u + it] = ri[0]; vals[ri[0]] = -INFINITY; }
    __syncthreads();
  }
}

// ---------------- V mean over L per (b, channel) ---------------------------
__global__ void k_vmean(const float* __restrict__ V, float* __restrict__ vm, int Lc) {
  int b = blockIdx.x, c = threadIdx.x;   // 512 threads
  float s = 0.f;
  for (int l = 0; l < Lc; l++) s += V[(b * Lc + l) * DMODEL + c];
  vm[b * DMODEL + c] = s / (float)Lc;
}

// ---------------- fill context with broadcast V-mean -----------------------
__global__ void k_ctx_fill(float* __restrict__ ctx, const float* __restrict__ vm, int Lc) {
  int g = blockIdx.x * blockDim.x + threadIdx.x;   // float4 index
  int total = BATCH * Lc * (DMODEL / 4);
  if (g >= total) return;
  int c4 = g & 127;
  int row = g >> 7;
  int b = row / Lc;
  reinterpret_cast<float4*>(ctx)[g] =
      reinterpret_cast<const float4*>(vm)[b * 128 + c4];
}

// ---------------- full attention for selected queries + scatter ------------
__global__ __launch_bounds__(256) void k_attn_ctx(
    const float* __restrict__ Q, const float* __restrict__ Km,
    const float* __restrict__ V, const int* __restrict__ mtop,
    float* __restrict__ ctx, int Lc, int u) {
  int bi = blockIdx.x;
  int i = bi % u;
  int h = (bi / u) & 7;
  int b = bi / (u * 8);
  int tid = threadIdx.x;           // 256
  __shared__ __align__(16) float qlds[DKH];
  __shared__ float s_lds[2048];
  __shared__ float red[256];
  __shared__ float part[4][DKH];
  int row = mtop[(b * NHEADS + h) * u + i];
  if (tid < DKH) qlds[tid] = Q[(b * Lc + row) * DMODEL + h * DKH + tid];
  __syncthreads();
  for (int k = tid; k < Lc; k += 256) {
    const float4* kp = reinterpret_cast<const float4*>(&Km[(b * Lc + k) * DMODEL + h * DKH]);
    const float4* qp = reinterpret_cast<const float4*>(qlds);
    float s = 0.f;
#pragma unroll
    for (int d = 0; d < 16; d++) {
      float4 kv = kp[d], qv = qp[d];
      s += qv.x * kv.x + qv.y * kv.y + qv.z * kv.z + qv.w * kv.w;
    }
    s_lds[k] = s * 0.125f;         // 1/sqrt(64)
  }
  __syncthreads();
  float mx = -INFINITY;
  for (int k = tid; k < Lc; k += 256) mx = fmaxf(mx, s_lds[k]);
  red[tid] = mx;
  __syncthreads();
  for (int s = 128; s > 0; s >>= 1) {
    if (tid < s) red[tid] = fmaxf(red[tid], red[tid + s]);
    __syncthreads();
  }
  mx = red[0];
  __syncthreads();
  float ls = 0.f;
  for (int k = tid; k < Lc; k += 256) {
    float w = expf(s_lds[k] - mx);
    s_lds[k] = w;
    ls += w;
  }
  red[tid] = ls;
  __syncthreads();
  for (int s = 128; s > 0; s >>= 1) {
    if (tid < s) red[tid] += red[tid + s];
    __syncthreads();
  }
  float denom = red[0];
  int g = tid >> 6, d = tid & 63;
  int chunk = Lc >> 2;
  float acc = 0.f;
  for (int k = g * chunk; k < (g + 1) * chunk; k++)
    acc = fmaf(s_lds[k], V[(b * Lc + k) * DMODEL + h * DKH + d], acc);
  part[g][d] = acc;
  __syncthreads();
  if (tid < DKH) {
    float tot = part[0][tid] + part[1][tid] + part[2][tid] + part[3][tid];
    ctx[(b * Lc + row) * DMODEL + h * DKH + tid] = tot / denom;
  }
}

// ---------------- y = LayerNorm(x + a) * g + b -----------------------------
__global__ void k_add_ln(const float* __restrict__ x, const float* __restrict__ a,
                         const float* __restrict__ g, const float* __restrict__ be,
                         float* __restrict__ y) {
  int row = blockIdx.x;
  int tid = threadIdx.x;           // 256, each float2
  __shared__ float red[256];
  float2 xv = reinterpret_cast<const float2*>(x)[row * 256 + tid];
  float2 av = reinterpret_cast<const float2*>(a)[row * 256 + tid];
  float vx = xv.x + av.x, vy = xv.y + av.y;
  red[tid] = vx + vy;
  __syncthreads();
  for (int s = 128; s > 0; s >>= 1) {
    if (tid < s) red[tid] += red[tid + s];
    __syncthreads();
  }
  float mean = red[0] * (1.0f / 512.0f);
  __syncthreads();
  float dx = vx - mean, dy = vy - mean;
  red[tid] = dx * dx + dy * dy;
  __syncthreads();
  for (int s = 128; s > 0; s >>= 1) {
    if (tid < s) red[tid] += red[tid + s];
    __syncthreads();
  }
  float rstd = rsqrtf(red[0] * (1.0f / 512.0f) + 1e-5f);
  int c = tid * 2;
  float2 o;
  o.x = dx * rstd * g[c] + be[c];
  o.y = dy * rstd * g[c + 1] + be[c + 1];
  reinterpret_cast<float2*>(y)[row * 256 + tid] = o;
}

// ---------------- conv weight transpose: wt[k*512+ci][c] = cw[c][ci][k] ----
__global__ void k_wt(const float* __restrict__ cw, float* __restrict__ wt) {
  int g = blockIdx.x * blockDim.x + threadIdx.x;
  if (g >= 1536 * 512) return;
  int c = g & 511;
  int kk = g >> 9;
  int k = kk / 512, ci = kk - k * 512;
  wt[g] = cw[c * 1536 + ci * 3 + k];
}

// ---------------- maxpool k=3 s=2 with -inf edge ---------------------------
__global__ void k_pool(const float* __restrict__ cv, float* __restrict__ out) {
  int g = blockIdx.x * blockDim.x + threadIdx.x;
  int total = BATCH * LL2 * DMODEL;
  if (g >= total) return;
  int c = g & 511;
  int rest = g >> 9;
  int i = rest & (LL2 - 1);
  int b = rest >> 10;
  int t0 = 2 * i - 1;
  float m = -INFINITY;
#pragma unroll
  for (int k = 0; k < 3; k++) {
    int t = t0 + k;
    if (t >= 0 && t < LL1) m = fmaxf(m, cv[(b * LL1 + t) * DMODEL + c]);
  }
  out[g] = m;
}

// ---------------- mean over rows -------------------------------------------
__global__ void k_mean_rows(const float* __restrict__ h, float* __restrict__ enc, int Lc) {
  int b = blockIdx.x, c = threadIdx.x;
  float s = 0.f;
  for (int l = 0; l < Lc; l++) s += h[(b * Lc + l) * DMODEL + c];
  enc[b * DMODEL + c] = s / (float)Lc;
}

// ---------------- whh transpose (2048,512)->(512,2048) ---------------------
__global__ void k_whht(const float* __restrict__ whh, float* __restrict__ whhT) {
  int g = blockIdx.x * blockDim.x + threadIdx.x;
  if (g >= 512 * 2048) return;
  int i = g >> 11, j = g & 2047;
  whhT[g] = whh[j * 512 + i];
}

// ---------------- gx = enc @ wih^T + bih -----------------------------------
__global__ void k_gx(const float* __restrict__ enc, const float* __restrict__ wih,
                     const float* __restrict__ bih, float* __restrict__ gx) {
  int g = blockIdx.x * blockDim.x + threadIdx.x;
  if (g >= BATCH * 2048) return;
  int b = g >> 11, j = g & 2047;
  const float4* wp = reinterpret_cast<const float4*>(&wih[j * 512]);
  const float4* ep = reinterpret_cast<const float4*>(&enc[b * 512]);
  float s = bih[j];
  for (int d = 0; d < 128; d++) {
    float4 w = wp[d], e = ep[d];
    s += w.x * e.x + w.y * e.y + w.z * e.z + w.w * e.w;
  }
  gx[g] = s;
}

// ---------------- persistent LSTM: one block per batch row -----------------
__global__ __launch_bounds__(512) void k_lstm(
    const float* __restrict__ gx, const float* __restrict__ whhT,
    const float* __restrict__ bhh, const float* __restrict__ ow,
    const float* __restrict__ ob, float* __restrict__ out) {
  int b = blockIdx.x;
  int tid = threadIdx.x;           // 512
  __shared__ float h_lds[512];
  __shared__ __align__(16) float g_lds[2048];
  __shared__ float red[8];
  float4 gxb = reinterpret_cast<const float4*>(gx)[b * 512 + tid];
  float4 bh4 = reinterpret_cast<const float4*>(bhh)[tid];
  gxb.x += bh4.x; gxb.y += bh4.y; gxb.z += bh4.z; gxb.w += bh4.w;
  float c_st = 0.f;
  float owv = ow[tid];
  h_lds[tid] = 0.f;
  __syncthreads();
  const float4* wp = reinterpret_cast<const float4*>(whhT);
  for (int t = 0; t < TPRED; t++) {
    float4 a0 = gxb;
    float4 a1 = {0, 0, 0, 0}, a2 = {0, 0, 0, 0}, a3 = {0, 0, 0, 0};
    for (int i = 0; i < 512; i += 4) {
      float h0 = h_lds[i], h1 = h_lds[i + 1], h2 = h_lds[i + 2], h3 = h_lds[i + 3];
      float4 w0 = wp[(i + 0) * 512 + tid];
      float4 w1 = wp[(i + 1) * 512 + tid];
      float4 w2 = wp[(i + 2) * 512 + tid];
      float4 w3 = wp[(i + 3) * 512 + tid];
      a0.x = fmaf(h0, w0.x, a0.x); a0.y = fmaf(h0, w0.y, a0.y);
      a0.z = fmaf(h0, w0.z, a0.z); a0.w = fmaf(h0, w0.w, a0.w);
      a1.x = fmaf(h1, w1.x, a1.x); a1.y = fmaf(h1, w1.y, a1.y);
      a1.z = fmaf(h1, w1.z, a1.z); a1.w = fmaf(h1, w1.w, a1.w);
      a2.x = fmaf(h2, w2.x, a2.x); a2.y = fmaf(h2, w2.y, a2.y);
      a2.z = fmaf(h2, w2.z, a2.z); a2.w = fmaf(h2, w2.w, a2.w);
      a3.x = fmaf(h3, w3.x, a3.x); a3.y = fmaf(h3, w3.y, a3.y);
      a3.z = fmaf(h3, w3.z, a3.z); a3.w = fmaf(h3, w3.w, a3.w);
    }
    float4 acc;
    acc.x = (a0.x + a1.x) + (a2.x + a3.x);
    acc.y = (a0.y + a1.y) + (a2.y + a3.y);
    acc.z = (a0.z + a1.z) + (a2.z + a3.z);
    acc.w = (a0.w + a1.w) + (a2.w + a3.w);
    reinterpret_cast<float4*>(g_lds)[tid] = acc;
    __syncthreads();
    float gi = g_lds[tid], gf = g_lds[512 + tid];
    float gg = g_lds[1024 + tid], go = g_lds[1536 + tid];
    c_st = sigm(gf) * c_st + sigm(gi) * tanhf(gg);
    float hn = sigm(go) * tanhf(c_st);
    h_lds[tid] = hn;
    float p = hn * owv;
    for (int off = 32; off > 0; off >>= 1) p += __shfl_down(p, off);
    if ((tid & 63) == 0) red[tid >> 6] = p;
    __syncthreads();
    if (tid == 0) {
      float s = 0.f;
#pragma unroll
      for (int w = 0; w < 8; w++) s += red[w];
      out[b * TPRED + t] = s + ob[0];
    }
    __syncthreads();
  }
}

// ---------------------------------------------------------------------------
extern "C" void kernel_launch(void* const* d_in, const int* in_sizes, int n_in,
                              void* d_out, int out_size, void* d_ws, size_t ws_size,
                              hipStream_t stream) {
  const float* x       = (const float*)d_in[0];
  const int*   idx1    = (const int*)d_in[1];
  const int*   idx2    = (const int*)d_in[2];
  const float* emb_w   = (const float*)d_in[3];
  const float* emb_b   = (const float*)d_in[4];
  const float* wq      = (const float*)d_in[5];
  const float* bq      = (const float*)d_in[6];
  const float* wk      = (const float*)d_in[7];
  const float* bk      = (const float*)d_in[8];
  const float* wv      = (const float*)d_in[9];
  const float* bv      = (const float*)d_in[10];
  const float* wo      = (const float*)d_in[11];
  const float* bo      = (const float*)d_in[12];
  const float* w1      = (const float*)d_in[13];
  const float* b1      = (const float*)d_in[14];
  const float* w2      = (const float*)d_in[15];
  const float* b2      = (const float*)d_in[16];
  const float* ln1g    = (const float*)d_in[17];
  const float* ln1b    = (const float*)d_in[18];
  const float* ln2g    = (const float*)d_in[19];
  const float* ln2b    = (const float*)d_in[20];
  const float* conv_w  = (const float*)d_in[21];
  const float* conv_b  = (const float*)d_in[22];
  const float* bn_g    = (const float*)d_in[23];
  const float* bn_b    = (const float*)d_in[24];
  const float* bn_m    = (const float*)d_in[25];
  const float* bn_v    = (const float*)d_in[26];
  const float* lstm_wih = (const float*)d_in[27];
  const float* lstm_whh = (const float*)d_in[28];
  const float* lstm_bih = (const float*)d_in[29];
  const float* lstm_bhh = (const float*)d_in[30];
  const float* out_w   = (const float*)d_in[31];
  const float* out_b   = (const float*)d_in[32];
  float* outp = (float*)d_out;

  // -------- workspace arena (5 x 32MB slots + 16MB smalls = 176MB) --------
  char* ws = (char*)d_ws;
  const size_t SLOT = 33554432;    // 32MB
  float* S0 = (float*)(ws + 0 * SLOT);
  float* S1 = (float*)(ws + 1 * SLOT);
  float* S2 = (float*)(ws + 2 * SLOT);
  float* S3 = (float*)(ws + 3 * SLOT);
  float* S4 = (float*)(ws + 4 * SLOT);
  char*  SM = ws + 5 * SLOT;
  float* Mbuf  = (float*)(SM + 0);            // 512KB max
  int*   mtop  = (int*)  (SM + (1 << 20));    // 10KB
  float* vmean = (float*)(SM + (1 << 20) + (1 << 16));
  float* wtbuf = (float*)(SM + (2 << 20));    // 3MB
  float* whhT  = (float*)(SM + (5 << 20));    // 4MB
  float* gxbuf = (float*)(SM + (9 << 20));    // 64KB
  float* encb  = (float*)(SM + (9 << 20) + (1 << 17));

  auto gemm = [&](const float* A, const float* W, const float* bias, float* C,
                  int M, int N, int K, int act) {
    dim3 g(N / 128, M / 128);
    if (act == 0)
      k_gemm<0, 0><<<g, 256, 0, stream>>>(A, W, bias, C, M, N, K, 0,
                                          nullptr, nullptr, nullptr, nullptr);
    else
      k_gemm<1, 0><<<g, 256, 0, stream>>>(A, W, bias, C, M, N, K, 0,
                                          nullptr, nullptr, nullptr, nullptr);
  };

  // one-time-per-call weight reshapes (deterministic, in-graph)
  k_whht<<<(512 * 2048) / 256, 256, 0, stream>>>(lstm_whh, whhT);
  k_wt<<<(1536 * 512) / 256, 256, 0, stream>>>(conv_w, wtbuf);

  // ---------------- embed + posenc -> S0 ----------------------------------
  k_embed<<<BATCH * LL1, 256, 0, stream>>>(x, emb_w, emb_b, S0);

  // ---------------- encoder layer 1 (L=2048, u=40) ------------------------
  {
    const int Lc = LL1, u = 40, M = BATCH * LL1;
    const float* lwq = wq, *lbq = bq, *lwk = wk, *lbk = bk;
    const float* lwv = wv, *lbv = bv, *lwo = wo, *lbo = bo;
    gemm(S0, lwq, lbq, S1, M, 512, 512, 0);   // Q
    gemm(S0, lwk, lbk, S2, M, 512, 512, 0);   // K
    gemm(S0, lwv, lbv, S3, M, 512, 512, 0);   // V
    k_qk_m<<<M, 320, 0, stream>>>(S1, S2, idx1, Mbuf, Lc, u);
    k_topk<<<64, 256, 0, stream>>>(Mbuf, mtop, Lc, u);
    k_vmean<<<BATCH, 512, 0, stream>>>(S3, vmean, Lc);
    k_ctx_fill<<<(BATCH * Lc * 128) / 256, 256, 0, stream>>>(S4, vmean, Lc);
    k_attn_ctx<<<BATCH * NHEADS * u, 256, 0, stream>>>(S1, S2, S3, mtop, S4, Lc, u);
    gemm(S4, lwo, lbo, S1, M, 512, 512, 0);   // attn out -> S1
    k_add_ln<<<M, 256, 0, stream>>>(S0, S1, ln1g, ln1b, S2);  // ln1 -> S2
    for (int c = 0; c < 4; c++) {             // FFN in 4096-row chunks
      gemm(S2 + (size_t)c * 4096 * 512, w1, b1, S3, 4096, 2048, 512, 1);
      gemm(S3, w2, b2, S4 + (size_t)c * 4096 * 512, 4096, 512, 2048, 0);
    }
    k_add_ln<<<M, 256, 0, stream>>>(S2, S4, ln2g, ln2b, S0);  // h1 -> S0
  }

  // ---------------- conv distill: S0 -> S2 (8,1024,512) -------------------
  {
    dim3 g(512 / 128, (BATCH * LL1) / 128);
    k_gemm<2, 1><<<g, 256, 0, stream>>>(S0, wtbuf, conv_b, S1,
                                        BATCH * LL1, 512, 1536, LL1,
                                        bn_m, bn_v, bn_g, bn_b);
    k_pool<<<(BATCH * LL2 * 512) / 256, 256, 0, stream>>>(S1, S2);
  }

  // ---------------- encoder layer 2 (L=1024, u=35) ------------------------
  {
    const int Lc = LL2, u = 35, M = BATCH * LL2;
    const size_t HALF = 4194304;              // 16MB in floats
    const float* lwq = wq + 512 * 512, *lbq = bq + 512;
    const float* lwk = wk + 512 * 512, *lbk = bk + 512;
    const float* lwv = wv + 512 * 512, *lbv = bv + 512;
    const float* lwo = wo + 512 * 512, *lbo = bo + 512;
    const float* lw1 = w1 + 512 * 2048, *lb1 = b1 + 2048;
    const float* lw2 = w2 + 2048 * 512, *lb2 = b2 + 512;
    float* Q2 = S3;            float* K2 = S3 + HALF;
    float* V2 = S1;            float* CT2 = S1 + HALF;
    float* AO2 = S4;           float* LN2A = S4 + HALF;
    gemm(S2, lwq, lbq, Q2, M, 512, 512, 0);
    gemm(S2, lwk, lbk, K2, M, 512, 512, 0);
    gemm(S2, lwv, lbv, V2, M, 512, 512, 0);
    k_qk_m<<<M, 320, 0, stream>>>(Q2, K2, idx2, Mbuf, Lc, u);
    k_topk<<<64, 256, 0, stream>>>(Mbuf, mtop, Lc, u);
    k_vmean<<<BATCH, 512, 0, stream>>>(V2, vmean, Lc);
    k_ctx_fill<<<(BATCH * Lc * 128) / 256, 256, 0, stream>>>(CT2, vmean, Lc);
    k_attn_ctx<<<BATCH * NHEADS * u, 256, 0, stream>>>(Q2, K2, V2, mtop, CT2, Lc, u);
    gemm(CT2, lwo, lbo, AO2, M, 512, 512, 0);
    k_add_ln<<<M, 256, 0, stream>>>(S2, AO2, ln1g + 512, ln1b + 512, LN2A);
    for (int c = 0; c < 2; c++) {             // FFN chunks (hid -> S0)
      gemm(LN2A + (size_t)c * 4096 * 512, lw1, lb1, S0, 4096, 2048, 512, 1);
      gemm(S0, lw2, lb2, S3 + (size_t)c * 4096 * 512, 4096, 512, 2048, 0);
    }
    k_add_ln<<<M, 256, 0, stream>>>(LN2A, S3, ln2g + 512, ln2b + 512, S2); // h3 -> S2
  }

  // ---------------- mean -> LSTM -> output --------------------------------
  k_mean_rows<<<BATCH, 512, 0, stream>>>(S2, encb, LL2);
  k_gx<<<(BATCH * 2048) / 256, 256, 0, stream>>>(encb, lstm_wih, lstm_bih, gxbuf);
  k_lstm<<<BATCH, 512, 0, stream>>>(gxbuf, whhT, lstm_bhh, out_w, out_b, outp);
}

// Round 2
// 4626.935 us; speedup vs baseline: 2.0781x; 2.0781x over previous
//
#include <hip/hip_runtime.h>
#include <hip/hip_bf16.h>
#include <math.h>

static constexpr int BATCH = 8;
static constexpr int LL1 = 2048;
static constexpr int LL2 = 1024;
static constexpr int DMODEL = 512;
static constexpr int NHEADS = 8;
static constexpr int DKH = 64;
static constexpr int TPRED = 100;

typedef unsigned short u16;
typedef unsigned int u32;
typedef __attribute__((ext_vector_type(8))) short short8;   // 8 bf16
typedef __attribute__((ext_vector_type(4))) float f32x4;

__device__ __forceinline__ float sigm(float x) { return 1.0f / (1.0f + expf(-x)); }

// bf16 split helpers (round-to-nearest-even)
__device__ __forceinline__ u16 f2b(float f) {
  u32 u = __builtin_bit_cast(u32, f);
  return (u16)((u + 0x7fffu + ((u >> 16) & 1u)) >> 16);
}
__device__ __forceinline__ float b2f(u16 h) {
  return __builtin_bit_cast(float, (u32)h << 16);
}

#define GLD16(gsrc, ldst) __builtin_amdgcn_global_load_lds( \
    (const __attribute__((address_space(1))) u32*)(gsrc),   \
    (__attribute__((address_space(3))) u32*)(ldst), 16, 0, 0)

// ---------------- embedding + posenc, writes fp32 + bf16-split -------------
__global__ void k_embed(const float* __restrict__ x, const float* __restrict__ ew,
                        const float* __restrict__ eb, float* __restrict__ out,
                        u16* __restrict__ oh, u16* __restrict__ ol) {
  int row = blockIdx.x;
  int l = row & (LL1 - 1);
  int tid = threadIdx.x;
  __shared__ float xr[64];
  if (tid < 64) xr[tid] = x[row * 64 + tid];
  __syncthreads();
  const float fac = -9.210340371976184f / 512.0f;
  for (int c = tid; c < DMODEL; c += 256) {
    float acc = eb[c];
#pragma unroll 8
    for (int i = 0; i < 64; i++) acc = fmaf(xr[i], ew[i * DMODEL + c], acc);
    float divv = expf((float)(2 * (c >> 1)) * fac);
    float ang = (float)l * divv;
    acc += (c & 1) ? cosf(ang) : sinf(ang);
    size_t o = (size_t)row * DMODEL + c;
    out[o] = acc;
    u16 hh = f2b(acc);
    oh[o] = hh;
    ol[o] = f2b(acc - b2f(hh));
  }
}

// ---------------- MFMA GEMM, bf16x2 split, C = A@B + bias ------------------
// A split arrays [M][K]; B split arrays [N][K] (pre-transposed).
// EPI: 0=bias, 1=bias+GELU, 2=bias+BN+ELU. CONV: conv1d row-gather on A.
// OSPLIT: write bf16-split instead of fp32.
template <int EPI, int CONV, int OSPLIT>
__global__ __launch_bounds__(256) void k_mgemm(
    const u16* __restrict__ Ah, const u16* __restrict__ Al,
    const u16* __restrict__ Bh, const u16* __restrict__ Bl,
    const float* __restrict__ bias,
    float* __restrict__ C, u16* __restrict__ Ch, u16* __restrict__ Cl,
    int M, int N, int K, int Lc,
    const float* __restrict__ p_m, const float* __restrict__ p_v,
    const float* __restrict__ p_g, const float* __restrict__ p_b) {
  __shared__ __align__(16) u16 As_h[4096], As_l[4096], Bs_h[4096], Bs_l[4096];
  const int tid = threadIdx.x;
  const int m0 = blockIdx.y * 128, n0 = blockIdx.x * 128;
  const int wid = tid >> 6, lane = tid & 63;
  const int wm = (wid & 1) * 64, wn = (wid >> 1) * 64;
  const int lr = lane >> 4, lc = lane & 15;
  f32x4 acc[4][4];
  f32x4 zz = {0.f, 0.f, 0.f, 0.f};
#pragma unroll
  for (int i = 0; i < 4; i++)
#pragma unroll
    for (int j = 0; j < 4; j++) acc[i][j] = zz;

  for (int k0 = 0; k0 < K; k0 += 32) {
#pragma unroll
    for (int pass = 0; pass < 2; pass++) {
      int c = tid + pass * 256;
      int mi = c >> 2, kc = (c & 3) * 8;
      size_t asrc;
      if (CONV) {
        int m = m0 + mi;
        int b = m / Lc, t = m - b * Lc;
        int kblk = k0 >> 9;
        int srow = b * Lc + (t + kblk - 1 + Lc) % Lc;
        asrc = (size_t)srow * 512 + (k0 - (kblk << 9)) + kc;
      } else {
        asrc = (size_t)(m0 + mi) * K + k0 + kc;
      }
      size_t bsrc = (size_t)(n0 + mi) * K + k0 + kc;
      u32 ldo = (u32)((wid * 64 + pass * 256) * 8);
      GLD16(Ah + asrc, As_h + ldo);
      GLD16(Al + asrc, As_l + ldo);
      GLD16(Bh + bsrc, Bs_h + ldo);
      GLD16(Bl + bsrc, Bs_l + ldo);
    }
    __syncthreads();
    short8 ah[4], alv[4], bh[4], blv[4];
#pragma unroll
    for (int i = 0; i < 4; i++) {
      int ar = (wm + i * 16 + lc) * 32 + lr * 8;
      int br = (wn + i * 16 + lc) * 32 + lr * 8;
      ah[i] = *(const short8*)&As_h[ar];
      alv[i] = *(const short8*)&As_l[ar];
      bh[i] = *(const short8*)&Bs_h[br];
      blv[i] = *(const short8*)&Bs_l[br];
    }
#pragma unroll
    for (int i = 0; i < 4; i++)
#pragma unroll
      for (int j = 0; j < 4; j++) {
        acc[i][j] = __builtin_amdgcn_mfma_f32_16x16x32_bf16(ah[i], bh[j], acc[i][j], 0, 0, 0);
        acc[i][j] = __builtin_amdgcn_mfma_f32_16x16x32_bf16(ah[i], blv[j], acc[i][j], 0, 0, 0);
        acc[i][j] = __builtin_amdgcn_mfma_f32_16x16x32_bf16(alv[i], bh[j], acc[i][j], 0, 0, 0);
      }
    __syncthreads();
  }
#pragma unroll
  for (int j = 0; j < 4; j++) {
    int col = n0 + wn + j * 16 + lc;
    float bs = bias[col];
    float bnA = 0.f, bnB = 0.f;
    if (EPI == 2) {
      bnA = rsqrtf(p_v[col] + 1e-5f) * p_g[col];
      bnB = p_b[col] - p_m[col] * bnA;
    }
#pragma unroll
    for (int i = 0; i < 4; i++) {
#pragma unroll
      for (int q = 0; q < 4; q++) {
        int row = m0 + wm + i * 16 + lr * 4 + q;
        float t = acc[i][j][q] + bs;
        if (EPI == 1) t = 0.5f * t * (1.0f + erff(t * 0.7071067811865475f));
        if (EPI == 2) { t = t * bnA + bnB; t = t > 0.f ? t : expm1f(t); }
        size_t o = (size_t)row * N + col;
        if (OSPLIT) {
          u16 hh = f2b(t);
          Ch[o] = hh;
          Cl[o] = f2b(t - b2f(hh));
        } else {
          C[o] = t;
        }
      }
    }
  }
}

// ---------------- weight split+transpose: src[K][N] -> dh/dl[N][K] ---------
__global__ void k_splitw(const float* __restrict__ src, u16* __restrict__ dh,
                         u16* __restrict__ dl, int K, int N) {
  int g = blockIdx.x * 256 + threadIdx.x;
  if (g >= K * N) return;
  int n = g / K, k = g - n * K;
  float v = src[(size_t)k * N + n];
  u16 hh = f2b(v);
  dh[g] = hh;
  dl[g] = f2b(v - b2f(hh));
}

// conv weight: cw[c][ci][tap] -> [c][k=tap*512+ci]
__global__ void k_splitcw(const float* __restrict__ cw, u16* __restrict__ dh,
                          u16* __restrict__ dl) {
  int g = blockIdx.x * 256 + threadIdx.x;
  if (g >= 512 * 1536) return;
  int c = g / 1536, k = g - c * 1536;
  int kblk = k >> 9, ci = k & 511;
  float v = cw[c * 1536 + ci * 3 + kblk];
  u16 hh = f2b(v);
  dh[g] = hh;
  dl[g] = f2b(v - b2f(hh));
}

// ---------------- sampled qk -> sparsity measure M -------------------------
__global__ void k_qk_m(const float* __restrict__ Q, const float* __restrict__ Km,
                       const int* __restrict__ idx, float* __restrict__ Mout,
                       int Lc, int u) {
  int row = blockIdx.x;
  int b = row / Lc, l = row - b * Lc;
  int tid = threadIdx.x;
  int nt = blockDim.x;
  __shared__ __align__(16) float qlds[DMODEL];
  __shared__ int ilds[40];
  __shared__ float qk[320];
  for (int i = tid; i < DMODEL; i += nt) qlds[i] = Q[(size_t)row * DMODEL + i];
  for (int i = tid; i < u; i += nt) ilds[i] = idx[l * u + i];
  __syncthreads();
  int tot = NHEADS * u;
  if (tid < tot) {
    int j = tid >> 3, h = tid & 7;
    int key = ilds[j];
    const float4* kp = reinterpret_cast<const float4*>(&Km[((size_t)b * Lc + key) * DMODEL + h * DKH]);
    const float4* qp = reinterpret_cast<const float4*>(&qlds[h * DKH]);
    float s = 0.f;
#pragma unroll
    for (int d = 0; d < 16; d++) {
      float4 kv = kp[d], qv = qp[d];
      s += qv.x * kv.x + qv.y * kv.y + qv.z * kv.z + qv.w * kv.w;
    }
    qk[tid] = s;
  }
  __syncthreads();
  if (tid < NHEADS) {
    int h = tid;
    float mx = -INFINITY, sm = 0.f;
    for (int j = 0; j < u; j++) {
      float v = qk[(j << 3) + h];
      mx = fmaxf(mx, v);
      sm += v;
    }
    Mout[((size_t)b * NHEADS + h) * Lc + l] = mx - sm / (float)Lc;
  }
}

// ---------------- top-u, lax.top_k tie-break -------------------------------
__global__ void k_topk(const float* __restrict__ Mv, int* __restrict__ mtop,
                       int Lc, int u) {
  int bh = blockIdx.x;
  int tid = threadIdx.x;
  __shared__ float vals[2048];
  __shared__ float rv[256];
  __shared__ int ri[256];
  for (int i = tid; i < Lc; i += 256) vals[i] = Mv[(size_t)bh * Lc + i];
  __syncthreads();
  for (int it = 0; it < u; it++) {
    float bvv = -INFINITY;
    int bii = 0x7fffffff;
    for (int i = tid; i < Lc; i += 256) {
      float v = vals[i];
      if (v > bvv) { bvv = v; bii = i; }
    }
    rv[tid] = bvv; ri[tid] = bii;
    __syncthreads();
    for (int s = 128; s > 0; s >>= 1) {
      if (tid < s) {
        float v2 = rv[tid + s]; int i2 = ri[tid + s];
        if (v2 > rv[tid] || (v2 == rv[tid] && i2 < ri[tid])) { rv[tid] = v2; ri[tid] = i2; }
      }
      __syncthreads();
    }
    if (tid == 0) { mtop[bh * u + it] = ri[0]; vals[ri[0]] = -INFINITY; }
    __syncthreads();
  }
}

// ---------------- column-sum two-phase -------------------------------------
__global__ void k_colsum1(const float* __restrict__ src, float* __restrict__ part,
                          int Lc, int rp) {
  int b = blockIdx.x, ch = blockIdx.y, c = threadIdx.x;
  const float* p = src + ((size_t)b * Lc + (size_t)ch * rp) * 512 + c;
  float s = 0.f;
  for (int r = 0; r < rp; r++) s += p[(size_t)r * 512];
  part[((b << 5) + ch) * 512 + c] = s;
}
__global__ void k_colsum2(const float* __restrict__ part, float* __restrict__ of,
                          u16* __restrict__ oh, u16* __restrict__ ol,
                          int nch, float scale) {
  int b = blockIdx.x, c = threadIdx.x;
  float s = 0.f;
  for (int i = 0; i < nch; i++) s += part[(b * nch + i) * 512 + c];
  s *= scale;
  if (of) of[b * 512 + c] = s;
  if (oh) {
    u16 hh = f2b(s);
    oh[b * 512 + c] = hh;
    ol[b * 512 + c] = f2b(s - b2f(hh));
  }
}

// ---------------- fill context (bf16-split) with V-mean --------------------
__global__ void k_ctx_fillb(u16* __restrict__ ch, u16* __restrict__ cl,
                            const u16* __restrict__ vh, const u16* __restrict__ vl,
                            int Lc) {
  int g = blockIdx.x * 256 + threadIdx.x;
  int total = BATCH * Lc * 128;
  if (g >= total) return;
  int c4 = g & 127;
  int row = g >> 7;
  int b = row / Lc;
  ((ushort4*)ch)[g] = ((const ushort4*)vh)[b * 128 + c4];
  ((ushort4*)cl)[g] = ((const ushort4*)vl)[b * 128 + c4];
}

// ---------------- full attention for selected queries + scatter ------------
__global__ __launch_bounds__(256) void k_attn_ctx(
    const float* __restrict__ Q, const float* __restrict__ Km,
    const float* __restrict__ V, const int* __restrict__ mtop,
    u16* __restrict__ ctxh, u16* __restrict__ ctxl, int Lc, int u) {
  int bi = blockIdx.x;
  int i = bi % u;
  int h = (bi / u) & 7;
  int b = bi / (u * 8);
  int tid = threadIdx.x;
  __shared__ __align__(16) float qlds[DKH];
  __shared__ float s_lds[2048];
  __shared__ float red[256];
  __shared__ float part[4][DKH];
  int row = mtop[(b * NHEADS + h) * u + i];
  if (tid < DKH) qlds[tid] = Q[((size_t)b * Lc + row) * DMODEL + h * DKH + tid];
  __syncthreads();
  for (int k = tid; k < Lc; k += 256) {
    const float4* kp = reinterpret_cast<const float4*>(&Km[((size_t)b * Lc + k) * DMODEL + h * DKH]);
    const float4* qp = reinterpret_cast<const float4*>(qlds);
    float s = 0.f;
#pragma unroll
    for (int d = 0; d < 16; d++) {
      float4 kv = kp[d], qv = qp[d];
      s += qv.x * kv.x + qv.y * kv.y + qv.z * kv.z + qv.w * kv.w;
    }
    s_lds[k] = s * 0.125f;
  }
  __syncthreads();
  float mx = -INFINITY;
  for (int k = tid; k < Lc; k += 256) mx = fmaxf(mx, s_lds[k]);
  red[tid] = mx;
  __syncthreads();
  for (int s = 128; s > 0; s >>= 1) {
    if (tid < s) red[tid] = fmaxf(red[tid], red[tid + s]);
    __syncthreads();
  }
  mx = red[0];
  __syncthreads();
  float ls = 0.f;
  for (int k = tid; k < Lc; k += 256) {
    float w = expf(s_lds[k] - mx);
    s_lds[k] = w;
    ls += w;
  }
  red[tid] = ls;
  __syncthreads();
  for (int s = 128; s > 0; s >>= 1) {
    if (tid < s) red[tid] += red[tid + s];
    __syncthreads();
  }
  float denom = red[0];
  int g = tid >> 6, d = tid & 63;
  int chunk = Lc >> 2;
  float acc = 0.f;
  for (int k = g * chunk; k < (g + 1) * chunk; k++)
    acc = fmaf(s_lds[k], V[((size_t)b * Lc + k) * DMODEL + h * DKH + d], acc);
  part[g][d] = acc;
  __syncthreads();
  if (tid < DKH) {
    float tot = (part[0][tid] + part[1][tid] + part[2][tid] + part[3][tid]) / denom;
    size_t o = ((size_t)b * Lc + row) * DMODEL + h * DKH + tid;
    u16 hh = f2b(tot);
    ctxh[o] = hh;
    ctxl[o] = f2b(tot - b2f(hh));
  }
}

// ---------------- y = LayerNorm(x+a)*g+b ; optional fp32 / split out -------
__global__ void k_add_ln(const float* __restrict__ x, const float* __restrict__ a,
                         const float* __restrict__ g, const float* __restrict__ be,
                         float* __restrict__ y, u16* __restrict__ yh,
                         u16* __restrict__ yl) {
  int row = blockIdx.x;
  int tid = threadIdx.x;
  __shared__ float red[256];
  float2 xv = reinterpret_cast<const float2*>(x)[(size_t)row * 256 + tid];
  float2 av = reinterpret_cast<const float2*>(a)[(size_t)row * 256 + tid];
  float vx = xv.x + av.x, vy = xv.y + av.y;
  red[tid] = vx + vy;
  __syncthreads();
  for (int s = 128; s > 0; s >>= 1) {
    if (tid < s) red[tid] += red[tid + s];
    __syncthreads();
  }
  float mean = red[0] * (1.0f / 512.0f);
  __syncthreads();
  float dx = vx - mean, dy = vy - mean;
  red[tid] = dx * dx + dy * dy;
  __syncthreads();
  for (int s = 128; s > 0; s >>= 1) {
    if (tid < s) red[tid] += red[tid + s];
    __syncthreads();
  }
  float rstd = rsqrtf(red[0] * (1.0f / 512.0f) + 1e-5f);
  int c = tid * 2;
  float ox = dx * rstd * g[c] + be[c];
  float oy = dy * rstd * g[c + 1] + be[c + 1];
  if (y) {
    float2 o = {ox, oy};
    reinterpret_cast<float2*>(y)[(size_t)row * 256 + tid] = o;
  }
  if (yh) {
    size_t base = (size_t)row * 512 + c;
    u16 h0 = f2b(ox), h1 = f2b(oy);
    yh[base] = h0; yh[base + 1] = h1;
    yl[base] = f2b(ox - b2f(h0));
    yl[base + 1] = f2b(oy - b2f(h1));
  }
}

// ---------------- maxpool k=3 s=2, fp32 + split out ------------------------
__global__ void k_pool(const float* __restrict__ cv, float* __restrict__ out,
                       u16* __restrict__ oh, u16* __restrict__ ol) {
  int g = blockIdx.x * 256 + threadIdx.x;
  int total = BATCH * LL2 * DMODEL;
  if (g >= total) return;
  int c = g & 511;
  int rest = g >> 9;
  int i = rest & (LL2 - 1);
  int b = rest >> 10;
  int t0 = 2 * i - 1;
  float m = -INFINITY;
#pragma unroll
  for (int k = 0; k < 3; k++) {
    int t = t0 + k;
    if (t >= 0 && t < LL1) m = fmaxf(m, cv[((size_t)b * LL1 + t) * DMODEL + c]);
  }
  out[g] = m;
  u16 hh = f2b(m);
  oh[g] = hh;
  ol[g] = f2b(m - b2f(hh));
}

// ---------------- gx = enc @ wih^T + bih (+ zero barrier counter) ----------
__global__ void k_gx(const float* __restrict__ enc, const float* __restrict__ wih,
                     const float* __restrict__ bih, float* __restrict__ gx,
                     unsigned* __restrict__ bar) {
  int g = blockIdx.x * 256 + threadIdx.x;
  if (g == 0) bar[0] = 0u;
  if (g >= BATCH * 2048) return;
  int b = g >> 11, j = g & 2047;
  const float4* wp = reinterpret_cast<const float4*>(&wih[(size_t)j * 512]);
  const float4* ep = reinterpret_cast<const float4*>(&enc[b * 512]);
  float s = bih[j];
  for (int d = 0; d < 128; d++) {
    float4 w = wp[d], e = ep[d];
    s += w.x * e.x + w.y * e.y + w.z * e.z + w.w * e.w;
  }
  gx[g] = s;
}

// ---------------- persistent multi-block LSTM, weights in registers --------
__global__ __launch_bounds__(256) void k_lstm2(
    const float* __restrict__ gx, const float* __restrict__ whh,
    const float* __restrict__ bhh, const float* __restrict__ ow,
    const float* __restrict__ ob, float* __restrict__ out,
    float* __restrict__ gates, unsigned* __restrict__ bar) {
  const int bl = blockIdx.x, tid = threadIdx.x;
  const int jl = tid & 31, part = tid >> 5;
  const int j0 = bl * 32;
  __shared__ float h_s[8][512];
  __shared__ float red[8][32][9];
  __shared__ float ow_s[512];
  float w[64];
  {
    const float* wr = &whh[(size_t)(j0 + jl) * 512 + part * 64];
#pragma unroll
    for (int r = 0; r < 64; r += 4) {
      float4 v = *(const float4*)&wr[r];
      w[r] = v.x; w[r + 1] = v.y; w[r + 2] = v.z; w[r + 3] = v.w;
    }
  }
  const float gxv = gx[(size_t)part * 2048 + j0 + jl] + bhh[j0 + jl];
  float cst[16];
#pragma unroll
  for (int q = 0; q < 16; q++) cst[q] = 0.f;
  for (int i = tid; i < 4096; i += 256) ((float*)h_s)[i] = 0.f;
  for (int i = tid; i < 512; i += 256) ow_s[i] = ow[i];
  const float obv = ob[0];
  __syncthreads();
  for (int t = 0; t < TPRED; t++) {
    float p[8];
#pragma unroll
    for (int b = 0; b < 8; b++) p[b] = 0.f;
#pragma unroll 4
    for (int r = 0; r < 64; r += 4) {
      float w0 = w[r], w1 = w[r + 1], w2 = w[r + 2], w3 = w[r + 3];
#pragma unroll
      for (int b = 0; b < 8; b++) {
        float4 hv = *(const float4*)&h_s[b][part * 64 + r];
        p[b] = fmaf(w3, hv.w, fmaf(w2, hv.z, fmaf(w1, hv.y, fmaf(w0, hv.x, p[b]))));
      }
    }
#pragma unroll
    for (int b = 0; b < 8; b++) red[part][jl][b] = p[b];
    __syncthreads();
    float gv = gxv;
#pragma unroll
    for (int pp = 0; pp < 8; pp++) gv += red[pp][jl][part];
    gates[(t & 1) * 16384 + part * 2048 + j0 + jl] = gv;
    __syncthreads();   // drains vmcnt: gate stores complete before arrival
    if (tid == 0) {
      __hip_atomic_fetch_add(bar, 1u, __ATOMIC_ACQ_REL, __HIP_MEMORY_SCOPE_AGENT);
      unsigned tgt = (unsigned)(t + 1) * 64u;
      while (__hip_atomic_load(bar, __ATOMIC_ACQUIRE, __HIP_MEMORY_SCOPE_AGENT) < tgt)
        __builtin_amdgcn_s_sleep(1);
    }
    __syncthreads();
    const float* G = gates + (t & 1) * 16384;
    float hq[16];
#pragma unroll
    for (int q = 0; q < 16; q++) {
      int f = q * 256 + tid;
      int b = f >> 9, m = f & 511;
      const float* Gb = G + b * 2048 + m;
      float gi = __hip_atomic_load(Gb, __ATOMIC_RELAXED, __HIP_MEMORY_SCOPE_AGENT);
      float gf = __hip_atomic_load(Gb + 512, __ATOMIC_RELAXED, __HIP_MEMORY_SCOPE_AGENT);
      float gg = __hip_atomic_load(Gb + 1024, __ATOMIC_RELAXED, __HIP_MEMORY_SCOPE_AGENT);
      float go = __hip_atomic_load(Gb + 1536, __ATOMIC_RELAXED, __HIP_MEMORY_SCOPE_AGENT);
      float c = sigm(gf) * cst[q] + sigm(gi) * tanhf(gg);
      cst[q] = c;
      hq[q] = sigm(go) * tanhf(c);
    }
#pragma unroll
    for (int q = 0; q < 16; q++) ((float*)h_s)[q * 256 + tid] = hq[q];
    __syncthreads();
    if (bl == 0) {
      int b = tid >> 5, l5 = tid & 31;
      float s = 0.f;
#pragma unroll
      for (int e = 0; e < 16; e++) s += h_s[b][l5 + (e << 5)] * ow_s[l5 + (e << 5)];
      s += __shfl_xor(s, 1); s += __shfl_xor(s, 2); s += __shfl_xor(s, 4);
      s += __shfl_xor(s, 8); s += __shfl_xor(s, 16);
      if (l5 == 0) out[b * TPRED + t] = s + obv;
    }
  }
}

// ---------------------------------------------------------------------------
extern "C" void kernel_launch(void* const* d_in, const int* in_sizes, int n_in,
                              void* d_out, int out_size, void* d_ws, size_t ws_size,
                              hipStream_t stream) {
  const float* x = (const float*)d_in[0];
  const int* idx1 = (const int*)d_in[1];
  const int* idx2 = (const int*)d_in[2];
  const float* emb_w = (const float*)d_in[3];
  const float* emb_b = (const float*)d_in[4];
  const float* wq = (const float*)d_in[5];
  const float* bq = (const float*)d_in[6];
  const float* wk = (const float*)d_in[7];
  const float* bk = (const float*)d_in[8];
  const float* wv = (const float*)d_in[9];
  const float* bv = (const float*)d_in[10];
  const float* wo = (const float*)d_in[11];
  const float* bo = (const float*)d_in[12];
  const float* w1 = (const float*)d_in[13];
  const float* b1 = (const float*)d_in[14];
  const float* w2 = (const float*)d_in[15];
  const float* b2 = (const float*)d_in[16];
  const float* ln1g = (const float*)d_in[17];
  const float* ln1b = (const float*)d_in[18];
  const float* ln2g = (const float*)d_in[19];
  const float* ln2b = (const float*)d_in[20];
  const float* conv_w = (const float*)d_in[21];
  const float* conv_b = (const float*)d_in[22];
  const float* bn_g = (const float*)d_in[23];
  const float* bn_b = (const float*)d_in[24];
  const float* bn_m = (const float*)d_in[25];
  const float* bn_v = (const float*)d_in[26];
  const float* lstm_wih = (const float*)d_in[27];
  const float* lstm_whh = (const float*)d_in[28];
  const float* lstm_bih = (const float*)d_in[29];
  const float* lstm_bhh = (const float*)d_in[30];
  const float* out_w = (const float*)d_in[31];
  const float* out_b = (const float*)d_in[32];
  float* outp = (float*)d_out;

  char* ws = (char*)d_ws;
  const size_t MB = 1 << 20;
  float* S0 = (float*)(ws);
  float* S1 = (float*)(ws + 32 * MB);
  float* S2 = (float*)(ws + 64 * MB);
  float* S3 = (float*)(ws + 96 * MB);
  u16* P0 = (u16*)(ws + 128 * MB);
  u16* P1 = (u16*)(ws + 144 * MB);
  u16* P2 = (u16*)(ws + 160 * MB);
  u16* P3 = (u16*)(ws + 176 * MB);
  u16* WATT = (u16*)(ws + 192 * MB);
  u16* W1T = (u16*)(ws + 200 * MB);
  u16* W2T = (u16*)(ws + 208 * MB);
  u16* CWT = (u16*)(ws + 216 * MB);
  char* SMB = ws + 220 * MB;
  float* Mbuf = (float*)(SMB);
  float* csp = (float*)(SMB + 512 * 1024);
  u16* vmh = (u16*)(SMB + 1040 * 1024);
  u16* vml = (u16*)(SMB + 1048 * 1024);
  int* mtop = (int*)(SMB + 1056 * 1024);
  float* gates = (float*)(SMB + 1088 * 1024);
  float* gxb = (float*)(SMB + 1216 * 1024);
  float* encb = (float*)(SMB + 1280 * 1024);
  unsigned* bar = (unsigned*)(SMB + 1296 * 1024);

  auto wat = [&](int l, int m, int hl) {
    return WATT + ((size_t)((l * 4 + m) * 2 + hl)) * 262144;
  };
  auto splitw = [&](const float* src, u16* dh, u16* dl, int K, int N) {
    int tot = K * N;
    k_splitw<<<(tot + 255) / 256, 256, 0, stream>>>(src, dh, dl, K, N);
  };
  for (int l = 0; l < 2; l++) {
    splitw(wq + (size_t)l * 262144, wat(l, 0, 0), wat(l, 0, 1), 512, 512);
    splitw(wk + (size_t)l * 262144, wat(l, 1, 0), wat(l, 1, 1), 512, 512);
    splitw(wv + (size_t)l * 262144, wat(l, 2, 0), wat(l, 2, 1), 512, 512);
    splitw(wo + (size_t)l * 262144, wat(l, 3, 0), wat(l, 3, 1), 512, 512);
    splitw(w1 + (size_t)l * 1048576, W1T + (size_t)(l * 2) * 1048576,
           W1T + (size_t)(l * 2 + 1) * 1048576, 512, 2048);
    splitw(w2 + (size_t)l * 1048576, W2T + (size_t)(l * 2) * 1048576,
           W2T + (size_t)(l * 2 + 1) * 1048576, 2048, 512);
  }
  k_splitcw<<<(512 * 1536 + 255) / 256, 256, 0, stream>>>(conv_w, CWT, CWT + 786432);

  auto mg = [&](const u16* Ah, const u16* Al, const u16* Bh, const u16* Bl,
                const float* bias, float* C, int M, int N, int K) {
    dim3 g(N / 128, M / 128);
    k_mgemm<0, 0, 0><<<g, 256, 0, stream>>>(Ah, Al, Bh, Bl, bias, C, nullptr, nullptr,
                                            M, N, K, 0, nullptr, nullptr, nullptr, nullptr);
  };

  // ---------------- embed ----------------
  k_embed<<<BATCH * LL1, 256, 0, stream>>>(x, emb_w, emb_b, S0, P0, P1);

  // ---------------- encoder layer 1 ----------------
  {
    const int Lc = LL1, u = 40, M = BATCH * LL1;
    mg(P0, P1, wat(0, 0, 0), wat(0, 0, 1), bq, S1, M, 512, 512);
    mg(P0, P1, wat(0, 1, 0), wat(0, 1, 1), bk, S2, M, 512, 512);
    mg(P0, P1, wat(0, 2, 0), wat(0, 2, 1), bv, S3, M, 512, 512);
    k_qk_m<<<M, 320, 0, stream>>>(S1, S2, idx1, Mbuf, Lc, u);
    k_topk<<<64, 256, 0, stream>>>(Mbuf, mtop, Lc, u);
    k_colsum1<<<dim3(BATCH, 32), 512, 0, stream>>>(S3, csp, Lc, Lc / 32);
    k_colsum2<<<BATCH, 512, 0, stream>>>(csp, nullptr, vmh, vml, 32, 1.f / Lc);
    k_ctx_fillb<<<(BATCH * Lc * 128) / 256, 256, 0, stream>>>(P2, P3, vmh, vml, Lc);
    k_attn_ctx<<<BATCH * 8 * u, 256, 0, stream>>>(S1, S2, S3, mtop, P2, P3, Lc, u);
    mg(P2, P3, wat(0, 3, 0), wat(0, 3, 1), bo, S1, M, 512, 512);
    k_add_ln<<<M, 256, 0, stream>>>(S0, S1, ln1g, ln1b, S2, P0, P1);
    for (int c = 0; c < 4; c++) {
      dim3 g1(16, 32);
      k_mgemm<1, 0, 1><<<g1, 256, 0, stream>>>(
          P0 + (size_t)c * 4096 * 512, P1 + (size_t)c * 4096 * 512,
          W1T, W1T + 1048576, b1, nullptr, P2, P3, 4096, 2048, 512, 0,
          nullptr, nullptr, nullptr, nullptr);
      dim3 g2(4, 32);
      k_mgemm<0, 0, 0><<<g2, 256, 0, stream>>>(
          P2, P3, W2T, W2T + 1048576, b2, S3 + (size_t)c * 4096 * 512,
          nullptr, nullptr, 4096, 512, 2048, 0, nullptr, nullptr, nullptr, nullptr);
    }
    k_add_ln<<<M, 256, 0, stream>>>(S2, S3, ln2g, ln2b, nullptr, P0, P1);
  }

  // ---------------- conv distill ----------------
  {
    dim3 g(4, 128);
    k_mgemm<2, 1, 0><<<g, 256, 0, stream>>>(P0, P1, CWT, CWT + 786432, conv_b,
                                            S1, nullptr, nullptr, 16384, 512, 1536,
                                            LL1, bn_m, bn_v, bn_g, bn_b);
    k_pool<<<(BATCH * LL2 * 512) / 256, 256, 0, stream>>>(S1, S2, P0, P1);
  }

  // ---------------- encoder layer 2 ----------------
  {
    const int Lc = LL2, u = 35, M = BATCH * LL2;
    float* Qb = S1;
    float* Kb = S1 + 4194304;
    float* Vb = S3;
    float* AOb = S3 + 4194304;
    mg(P0, P1, wat(1, 0, 0), wat(1, 0, 1), bq + 512, Qb, M, 512, 512);
    mg(P0, P1, wat(1, 1, 0), wat(1, 1, 1), bk + 512, Kb, M, 512, 512);
    mg(P0, P1, wat(1, 2, 0), wat(1, 2, 1), bv + 512, Vb, M, 512, 512);
    k_qk_m<<<M, 320, 0, stream>>>(Qb, Kb, idx2, Mbuf, Lc, u);
    k_topk<<<64, 256, 0, stream>>>(Mbuf, mtop, Lc, u);
    k_colsum1<<<dim3(BATCH, 32), 512, 0, stream>>>(Vb, csp, Lc, Lc / 32);
    k_colsum2<<<BATCH, 512, 0, stream>>>(csp, nullptr, vmh, vml, 32, 1.f / Lc);
    k_ctx_fillb<<<(BATCH * Lc * 128) / 256, 256, 0, stream>>>(P2, P3, vmh, vml, Lc);
    k_attn_ctx<<<BATCH * 8 * u, 256, 0, stream>>>(Qb, Kb, Vb, mtop, P2, P3, Lc, u);
    mg(P2, P3, wat(1, 3, 0), wat(1, 3, 1), bo + 512, AOb, M, 512, 512);
    k_add_ln<<<M, 256, 0, stream>>>(S2, AOb, ln1g + 512, ln1b + 512, S0, P0, P1);
    for (int c = 0; c < 2; c++) {
      dim3 g1(16, 32);
      k_mgemm<1, 0, 1><<<g1, 256, 0, stream>>>(
          P0 + (size_t)c * 4096 * 512, P1 + (size_t)c * 4096 * 512,
          W1T + (size_t)2 * 1048576, W1T + (size_t)3 * 1048576, b1 + 2048,
          nullptr, P2, P3, 4096, 2048, 512, 0, nullptr, nullptr, nullptr, nullptr);
      dim3 g2(4, 32);
      k_mgemm<0, 0, 0><<<g2, 256, 0, stream>>>(
          P2, P3, W2T + (size_t)2 * 1048576, W2T + (size_t)3 * 1048576, b2 + 512,
          S1 + (size_t)c * 4096 * 512, nullptr, nullptr, 4096, 512, 2048, 0,
          nullptr, nullptr, nullptr, nullptr);
    }
    k_add_ln<<<M, 256, 0, stream>>>(S0, S1, ln2g + 512, ln2b + 512, S2, nullptr, nullptr);
  }

  // ---------------- mean -> LSTM -> output ----------------
  k_colsum1<<<dim3(BATCH, 32), 512, 0, stream>>>(S2, csp, LL2, LL2 / 32);
  k_colsum2<<<BATCH, 512, 0, stream>>>(csp, encb, nullptr, nullptr, 32, 1.f / LL2);
  k_gx<<<(BATCH * 2048) / 256, 256, 0, stream>>>(encb, lstm_wih, lstm_bih, gxb, bar);
  k_lstm2<<<64, 256, 0, stream>>>(gxb, lstm_whh, lstm_bhh, out_w, out_b, outp, gates, bar);
}

// Round 4
// 3723.039 us; speedup vs baseline: 2.5826x; 1.2428x over previous
//
#include <hip/hip_runtime.h>
#include <hip/hip_bf16.h>
#include <math.h>

static constexpr int BATCH = 8;
static constexpr int LL1 = 2048;
static constexpr int LL2 = 1024;
static constexpr int DMODEL = 512;
static constexpr int NHEADS = 8;
static constexpr int DKH = 64;
static constexpr int TPRED = 100;

typedef unsigned short u16;
typedef unsigned int u32;
typedef unsigned long long u64;
typedef __attribute__((ext_vector_type(8))) short short8;   // 8 bf16
typedef __attribute__((ext_vector_type(4))) float f32x4;

__device__ __forceinline__ float sigm(float x) { return 1.0f / (1.0f + expf(-x)); }

// bf16 split helpers (round-to-nearest-even)
__device__ __forceinline__ u16 f2b(float f) {
  u32 u = __builtin_bit_cast(u32, f);
  return (u16)((u + 0x7fffu + ((u >> 16) & 1u)) >> 16);
}
__device__ __forceinline__ float b2f(u16 h) {
  return __builtin_bit_cast(float, (u32)h << 16);
}

#define GLD16(gsrc, ldst) __builtin_amdgcn_global_load_lds( \
    (const __attribute__((address_space(1))) u32*)(gsrc),   \
    (__attribute__((address_space(3))) u32*)(ldst), 16, 0, 0)

// ---------------- embedding + posenc, writes fp32 + bf16-split -------------
__global__ void k_embed(const float* __restrict__ x, const float* __restrict__ ew,
                        const float* __restrict__ eb, float* __restrict__ out,
                        u16* __restrict__ oh, u16* __restrict__ ol) {
  int row = blockIdx.x;
  int l = row & (LL1 - 1);
  int tid = threadIdx.x;
  __shared__ float xr[64];
  if (tid < 64) xr[tid] = x[row * 64 + tid];
  __syncthreads();
  const float fac = -9.210340371976184f / 512.0f;
  for (int c = tid; c < DMODEL; c += 256) {
    float acc = eb[c];
#pragma unroll 8
    for (int i = 0; i < 64; i++) acc = fmaf(xr[i], ew[i * DMODEL + c], acc);
    float divv = expf((float)(2 * (c >> 1)) * fac);
    float ang = (float)l * divv;
    acc += (c & 1) ? cosf(ang) : sinf(ang);
    size_t o = (size_t)row * DMODEL + c;
    out[o] = acc;
    u16 hh = f2b(acc);
    oh[o] = hh;
    ol[o] = f2b(acc - b2f(hh));
  }
}

// ---------------- MFMA GEMM, bf16x2 split, C = A@B + bias ------------------
template <int EPI, int CONV, int OSPLIT>
__global__ __launch_bounds__(256) void k_mgemm(
    const u16* __restrict__ Ah, const u16* __restrict__ Al,
    const u16* __restrict__ Bh, const u16* __restrict__ Bl,
    const float* __restrict__ bias,
    float* __restrict__ C, u16* __restrict__ Ch, u16* __restrict__ Cl,
    int M, int N, int K, int Lc,
    const float* __restrict__ p_m, const float* __restrict__ p_v,
    const float* __restrict__ p_g, const float* __restrict__ p_b) {
  __shared__ __align__(16) u16 As_h[4096], As_l[4096], Bs_h[4096], Bs_l[4096];
  const int tid = threadIdx.x;
  const int m0 = blockIdx.y * 128, n0 = blockIdx.x * 128;
  const int wid = tid >> 6, lane = tid & 63;
  const int wm = (wid & 1) * 64, wn = (wid >> 1) * 64;
  const int lr = lane >> 4, lc = lane & 15;
  f32x4 acc[4][4];
  f32x4 zz = {0.f, 0.f, 0.f, 0.f};
#pragma unroll
  for (int i = 0; i < 4; i++)
#pragma unroll
    for (int j = 0; j < 4; j++) acc[i][j] = zz;

  for (int k0 = 0; k0 < K; k0 += 32) {
#pragma unroll
    for (int pass = 0; pass < 2; pass++) {
      int c = tid + pass * 256;
      int mi = c >> 2, kc = (c & 3) * 8;
      size_t asrc;
      if (CONV) {
        int m = m0 + mi;
        int b = m / Lc, t = m - b * Lc;
        int kblk = k0 >> 9;
        int srow = b * Lc + (t + kblk - 1 + Lc) % Lc;
        asrc = (size_t)srow * 512 + (k0 - (kblk << 9)) + kc;
      } else {
        asrc = (size_t)(m0 + mi) * K + k0 + kc;
      }
      size_t bsrc = (size_t)(n0 + mi) * K + k0 + kc;
      u32 ldo = (u32)((wid * 64 + pass * 256) * 8);
      GLD16(Ah + asrc, As_h + ldo);
      GLD16(Al + asrc, As_l + ldo);
      GLD16(Bh + bsrc, Bs_h + ldo);
      GLD16(Bl + bsrc, Bs_l + ldo);
    }
    __syncthreads();
    short8 ah[4], alv[4], bh[4], blv[4];
#pragma unroll
    for (int i = 0; i < 4; i++) {
      int ar = (wm + i * 16 + lc) * 32 + lr * 8;
      int br = (wn + i * 16 + lc) * 32 + lr * 8;
      ah[i] = *(const short8*)&As_h[ar];
      alv[i] = *(const short8*)&As_l[ar];
      bh[i] = *(const short8*)&Bs_h[br];
      blv[i] = *(const short8*)&Bs_l[br];
    }
#pragma unroll
    for (int i = 0; i < 4; i++)
#pragma unroll
      for (int j = 0; j < 4; j++) {
        acc[i][j] = __builtin_amdgcn_mfma_f32_16x16x32_bf16(ah[i], bh[j], acc[i][j], 0, 0, 0);
        acc[i][j] = __builtin_amdgcn_mfma_f32_16x16x32_bf16(ah[i], blv[j], acc[i][j], 0, 0, 0);
        acc[i][j] = __builtin_amdgcn_mfma_f32_16x16x32_bf16(alv[i], bh[j], acc[i][j], 0, 0, 0);
      }
    __syncthreads();
  }
#pragma unroll
  for (int j = 0; j < 4; j++) {
    int col = n0 + wn + j * 16 + lc;
    float bs = bias[col];
    float bnA = 0.f, bnB = 0.f;
    if (EPI == 2) {
      bnA = rsqrtf(p_v[col] + 1e-5f) * p_g[col];
      bnB = p_b[col] - p_m[col] * bnA;
    }
#pragma unroll
    for (int i = 0; i < 4; i++) {
#pragma unroll
      for (int q = 0; q < 4; q++) {
        int row = m0 + wm + i * 16 + lr * 4 + q;
        float t = acc[i][j][q] + bs;
        if (EPI == 1) t = 0.5f * t * (1.0f + erff(t * 0.7071067811865475f));
        if (EPI == 2) { t = t * bnA + bnB; t = t > 0.f ? t : expm1f(t); }
        size_t o = (size_t)row * N + col;
        if (OSPLIT) {
          u16 hh = f2b(t);
          Ch[o] = hh;
          Cl[o] = f2b(t - b2f(hh));
        } else {
          C[o] = t;
        }
      }
    }
  }
}

// ---------------- fused weight split/transpose (all weights, 1 dispatch) ---
__global__ void k_splitall(const float* __restrict__ wq, const float* __restrict__ wk,
                           const float* __restrict__ wv, const float* __restrict__ wo,
                           const float* __restrict__ w1, const float* __restrict__ w2,
                           const float* __restrict__ cw,
                           u16* __restrict__ WATT, u16* __restrict__ W1T,
                           u16* __restrict__ W2T, u16* __restrict__ CWT) {
  int job = blockIdx.y;
  int g = blockIdx.x * 256 + threadIdx.x;
  float v;
  u16 *dh, *dl;
  if (job < 8) {
    if (g >= 262144) return;
    int l = job >> 2, mi = job & 3;
    const float* src = (mi == 0 ? wq : mi == 1 ? wk : mi == 2 ? wv : wo) + (size_t)l * 262144;
    int n = g >> 9, k = g & 511;
    v = src[(size_t)k * 512 + n];
    dh = WATT + (size_t)((l * 4 + mi) * 2) * 262144;
    dl = dh + 262144;
  } else if (job == 8 || job == 10) {           // w1: K=512, N=2048
    if (g >= 1048576) return;
    int l = (job == 10);
    int n = g >> 9, k = g & 511;
    v = w1[(size_t)l * 1048576 + (size_t)k * 2048 + n];
    dh = W1T + (size_t)(l * 2) * 1048576;
    dl = dh + 1048576;
  } else if (job == 9 || job == 11) {           // w2: K=2048, N=512
    if (g >= 1048576) return;
    int l = (job == 11);
    int n = g >> 11, k = g & 2047;
    v = w2[(size_t)l * 1048576 + (size_t)k * 512 + n];
    dh = W2T + (size_t)(l * 2) * 1048576;
    dl = dh + 1048576;
  } else {                                       // conv
    if (g >= 786432) return;
    int c = g / 1536, k = g - c * 1536;
    int kblk = k >> 9, ci = k & 511;
    v = cw[c * 1536 + ci * 3 + kblk];
    dh = CWT;
    dl = CWT + 786432;
  }
  u16 hh = f2b(v);
  dh[g] = hh;
  dl[g] = f2b(v - b2f(hh));
}

// ---------------- sampled qk -> sparsity measure M -------------------------
__global__ void k_qk_m(const float* __restrict__ Q, const float* __restrict__ Km,
                       const int* __restrict__ idx, float* __restrict__ Mout,
                       int Lc, int u) {
  int row = blockIdx.x;
  int b = row / Lc, l = row - b * Lc;
  int tid = threadIdx.x;
  int nt = blockDim.x;
  __shared__ __align__(16) float qlds[DMODEL];
  __shared__ int ilds[40];
  __shared__ float qk[320];
  for (int i = tid; i < DMODEL; i += nt) qlds[i] = Q[(size_t)row * DMODEL + i];
  for (int i = tid; i < u; i += nt) ilds[i] = idx[l * u + i];
  __syncthreads();
  int tot = NHEADS * u;
  if (tid < tot) {
    int j = tid >> 3, h = tid & 7;
    int key = ilds[j];
    const float4* kp = reinterpret_cast<const float4*>(&Km[((size_t)b * Lc + key) * DMODEL + h * DKH]);
    const float4* qp = reinterpret_cast<const float4*>(&qlds[h * DKH]);
    float s = 0.f;
#pragma unroll
    for (int d = 0; d < 16; d++) {
      float4 kv = kp[d], qv = qp[d];
      s += qv.x * kv.x + qv.y * kv.y + qv.z * kv.z + qv.w * kv.w;
    }
    qk[tid] = s;
  }
  __syncthreads();
  if (tid < NHEADS) {
    int h = tid;
    float mx = -INFINITY, sm = 0.f;
    for (int j = 0; j < u; j++) {
      float v = qk[(j << 3) + h];
      mx = fmaxf(mx, v);
      sm += v;
    }
    Mout[((size_t)b * NHEADS + h) * Lc + l] = mx - sm / (float)Lc;
  }
}

// ---------------- top-u via packed u64 keys + wave shuffles ----------------
__global__ void k_topk(const float* __restrict__ Mv, int* __restrict__ mtop,
                       int Lc, int u) {
  int bh = blockIdx.x;
  int tid = threadIdx.x;
  int lane = tid & 63, wv = tid >> 6;
  __shared__ float vals[2048];
  __shared__ u64 wred[4];
  for (int i = tid; i < Lc; i += 256) vals[i] = Mv[(size_t)bh * Lc + i];
  __syncthreads();
  for (int it = 0; it < u; it++) {
    u64 best = 0;
    for (int i = tid; i < Lc; i += 256) {
      u32 ub = __builtin_bit_cast(u32, vals[i]);
      ub = (ub & 0x80000000u) ? ~ub : (ub | 0x80000000u);
      u64 key = ((u64)ub << 32) | (u64)(0xFFFFFFFFu - (u32)i);   // lower idx wins ties
      best = best > key ? best : key;
    }
#pragma unroll
    for (int o = 32; o > 0; o >>= 1) {
      u64 other = __shfl_xor(best, o);
      best = best > other ? best : other;
    }
    if (lane == 0) wred[wv] = best;
    __syncthreads();
    u64 b01 = wred[0] > wred[1] ? wred[0] : wred[1];
    u64 b23 = wred[2] > wred[3] ? wred[2] : wred[3];
    u64 b0 = b01 > b23 ? b01 : b23;
    int bi = (int)(0xFFFFFFFFu - (u32)(b0 & 0xFFFFFFFFu));
    if (tid == 0) {
      mtop[bh * u + it] = bi;
      vals[bi] = -INFINITY;
    }
    __syncthreads();
  }
}

// ---------------- column-sum two-phase -------------------------------------
__global__ void k_colsum1(const float* __restrict__ src, float* __restrict__ part,
                          int Lc, int rp) {
  int b = blockIdx.x, ch = blockIdx.y, c = threadIdx.x;
  const float* p = src + ((size_t)b * Lc + (size_t)ch * rp) * 512 + c;
  float s = 0.f;
  for (int r = 0; r < rp; r++) s += p[(size_t)r * 512];
  part[((b << 5) + ch) * 512 + c] = s;
}
__global__ void k_colsum2(const float* __restrict__ part, float* __restrict__ of,
                          u16* __restrict__ oh, u16* __restrict__ ol,
                          int nch, float scale) {
  int b = blockIdx.x, c = threadIdx.x;
  float s = 0.f;
  for (int i = 0; i < nch; i++) s += part[(b * nch + i) * 512 + c];
  s *= scale;
  if (of) of[b * 512 + c] = s;
  if (oh) {
    u16 hh = f2b(s);
    oh[b * 512 + c] = hh;
    ol[b * 512 + c] = f2b(s - b2f(hh));
  }
}

// ---------------- fill context (bf16-split) with V-mean --------------------
__global__ void k_ctx_fillb(u16* __restrict__ ch, u16* __restrict__ cl,
                            const u16* __restrict__ vh, const u16* __restrict__ vl,
                            int Lc) {
  int g = blockIdx.x * 256 + threadIdx.x;
  int total = BATCH * Lc * 128;
  if (g >= total) return;
  int c4 = g & 127;
  int row = g >> 7;
  int b = row / Lc;
  ((ushort4*)ch)[g] = ((const ushort4*)vh)[b * 128 + c4];
  ((ushort4*)cl)[g] = ((const ushort4*)vl)[b * 128 + c4];
}

// ---------------- attention: 5 queries per block + scatter -----------------
__global__ __launch_bounds__(256) void k_attn_mq(
    const float* __restrict__ Q, const float* __restrict__ Km,
    const float* __restrict__ V, const int* __restrict__ mtop,
    u16* __restrict__ ctxh, u16* __restrict__ ctxl, int Lc, int u, int nqb) {
  int blk = blockIdx.x;
  int qb = blk % nqb;
  int bh = blk / nqb;
  int h = bh & 7, b = bh >> 3;
  int tid = threadIdx.x;
  int lane = tid & 63, wv = tid >> 6;
  __shared__ __align__(16) float qlds[5][64];
  __shared__ float s_lds[5][2048];
  __shared__ float wredA[4], wredB[4];
  __shared__ int rows_s[5];
  __shared__ float part[4][5][64];
  // load 5 query vectors (strided: 320 elements with 256 threads)
  for (int qq = tid; qq < 320; qq += 256) {
    int q = qq >> 6, d = qq & 63;
    int row = mtop[(b * 8 + h) * u + qb * 5 + q];
    if (d == 0) rows_s[q] = row;
    qlds[q][d] = Q[((size_t)b * Lc + row) * DMODEL + h * DKH + d];
  }
  __syncthreads();
  // scores: K row reused across the 5 queries
  for (int k = tid; k < Lc; k += 256) {
    const float4* kp = reinterpret_cast<const float4*>(&Km[((size_t)b * Lc + k) * DMODEL + h * DKH]);
    float s0 = 0, s1 = 0, s2 = 0, s3 = 0, s4 = 0;
#pragma unroll
    for (int d = 0; d < 16; d++) {
      float4 kv = kp[d];
      float4 q0 = ((const float4*)qlds[0])[d];
      float4 q1 = ((const float4*)qlds[1])[d];
      float4 q2 = ((const float4*)qlds[2])[d];
      float4 q3 = ((const float4*)qlds[3])[d];
      float4 q4 = ((const float4*)qlds[4])[d];
      s0 += q0.x * kv.x + q0.y * kv.y + q0.z * kv.z + q0.w * kv.w;
      s1 += q1.x * kv.x + q1.y * kv.y + q1.z * kv.z + q1.w * kv.w;
      s2 += q2.x * kv.x + q2.y * kv.y + q2.z * kv.z + q2.w * kv.w;
      s3 += q3.x * kv.x + q3.y * kv.y + q3.z * kv.z + q3.w * kv.w;
      s4 += q4.x * kv.x + q4.y * kv.y + q4.z * kv.z + q4.w * kv.w;
    }
    s_lds[0][k] = s0 * 0.125f;
    s_lds[1][k] = s1 * 0.125f;
    s_lds[2][k] = s2 * 0.125f;
    s_lds[3][k] = s3 * 0.125f;
    s_lds[4][k] = s4 * 0.125f;
  }
  __syncthreads();
  float denomv[5];
#pragma unroll
  for (int q = 0; q < 5; q++) {
    float mx = -INFINITY;
    for (int k = tid; k < Lc; k += 256) mx = fmaxf(mx, s_lds[q][k]);
#pragma unroll
    for (int o = 32; o > 0; o >>= 1) mx = fmaxf(mx, __shfl_xor(mx, o));
    if (lane == 0) wredA[wv] = mx;
    __syncthreads();
    mx = fmaxf(fmaxf(wredA[0], wredA[1]), fmaxf(wredA[2], wredA[3]));
    float ls = 0.f;
    for (int k = tid; k < Lc; k += 256) {
      float w = expf(s_lds[q][k] - mx);
      s_lds[q][k] = w;
      ls += w;
    }
#pragma unroll
    for (int o = 32; o > 0; o >>= 1) ls += __shfl_xor(ls, o);
    if (lane == 0) wredB[wv] = ls;
    __syncthreads();
    denomv[q] = (wredB[0] + wredB[1]) + (wredB[2] + wredB[3]);
  }
  // PV: V row reused across queries; 4 k-chunks x 64 dims
  float acc0 = 0, acc1 = 0, acc2 = 0, acc3 = 0, acc4 = 0;
  int chunk = Lc >> 2;
  for (int k = wv * chunk; k < (wv + 1) * chunk; k++) {
    float vvv = V[((size_t)b * Lc + k) * DMODEL + h * DKH + lane];
    acc0 = fmaf(s_lds[0][k], vvv, acc0);
    acc1 = fmaf(s_lds[1][k], vvv, acc1);
    acc2 = fmaf(s_lds[2][k], vvv, acc2);
    acc3 = fmaf(s_lds[3][k], vvv, acc3);
    acc4 = fmaf(s_lds[4][k], vvv, acc4);
  }
  part[wv][0][lane] = acc0;
  part[wv][1][lane] = acc1;
  part[wv][2][lane] = acc2;
  part[wv][3][lane] = acc3;
  part[wv][4][lane] = acc4;
  __syncthreads();
  for (int q = wv; q < 5; q += 4) {
    float tot = ((part[0][q][lane] + part[1][q][lane]) +
                 (part[2][q][lane] + part[3][q][lane])) / denomv[q];
    size_t o = ((size_t)b * Lc + rows_s[q]) * DMODEL + h * DKH + lane;
    u16 hh = f2b(tot);
    ctxh[o] = hh;
    ctxl[o] = f2b(tot - b2f(hh));
  }
}

// ---------------- y = LayerNorm(x+a)*g+b ; optional fp32 / split out -------
__global__ void k_add_ln(const float* __restrict__ x, const float* __restrict__ a,
                         const float* __restrict__ g, const float* __restrict__ be,
                         float* __restrict__ y, u16* __restrict__ yh,
                         u16* __restrict__ yl) {
  int row = blockIdx.x;
  int tid = threadIdx.x;
  __shared__ float red[256];
  float2 xv = reinterpret_cast<const float2*>(x)[(size_t)row * 256 + tid];
  float2 av = reinterpret_cast<const float2*>(a)[(size_t)row * 256 + tid];
  float vx = xv.x + av.x, vy = xv.y + av.y;
  red[tid] = vx + vy;
  __syncthreads();
  for (int s = 128; s > 0; s >>= 1) {
    if (tid < s) red[tid] += red[tid + s];
    __syncthreads();
  }
  float mean = red[0] * (1.0f / 512.0f);
  __syncthreads();
  float dx = vx - mean, dy = vy - mean;
  red[tid] = dx * dx + dy * dy;
  __syncthreads();
  for (int s = 128; s > 0; s >>= 1) {
    if (tid < s) red[tid] += red[tid + s];
    __syncthreads();
  }
  float rstd = rsqrtf(red[0] * (1.0f / 512.0f) + 1e-5f);
  int c = tid * 2;
  float ox = dx * rstd * g[c] + be[c];
  float oy = dy * rstd * g[c + 1] + be[c + 1];
  if (y) {
    float2 o = {ox, oy};
    reinterpret_cast<float2*>(y)[(size_t)row * 256 + tid] = o;
  }
  if (yh) {
    size_t base = (size_t)row * 512 + c;
    u16 h0 = f2b(ox), h1 = f2b(oy);
    yh[base] = h0; yh[base + 1] = h1;
    yl[base] = f2b(ox - b2f(h0));
    yl[base + 1] = f2b(oy - b2f(h1));
  }
}

// ---------------- maxpool k=3 s=2, fp32 + split out ------------------------
__global__ void k_pool(const float* __restrict__ cv, float* __restrict__ out,
                       u16* __restrict__ oh, u16* __restrict__ ol) {
  int g = blockIdx.x * 256 + threadIdx.x;
  int total = BATCH * LL2 * DMODEL;
  if (g >= total) return;
  int c = g & 511;
  int rest = g >> 9;
  int i = rest & (LL2 - 1);
  int b = rest >> 10;
  int t0 = 2 * i - 1;
  float m = -INFINITY;
#pragma unroll
  for (int k = 0; k < 3; k++) {
    int t = t0 + k;
    if (t >= 0 && t < LL1) m = fmaxf(m, cv[((size_t)b * LL1 + t) * DMODEL + c]);
  }
  out[g] = m;
  u16 hh = f2b(m);
  oh[g] = hh;
  ol[g] = f2b(m - b2f(hh));
}

// ---------------- gx = enc @ wih^T + bih (+ zero lstm flags) ---------------
__global__ void k_gx(const float* __restrict__ enc, const float* __restrict__ wih,
                     const float* __restrict__ bih, float* __restrict__ gx,
                     unsigned* __restrict__ flags) {
  int g = blockIdx.x * 256 + threadIdx.x;
  if (g < 64) flags[g] = 0u;
  if (g >= BATCH * 2048) return;
  int b = g >> 11, j = g & 2047;
  const float4* wp = reinterpret_cast<const float4*>(&wih[(size_t)j * 512]);
  const float4* ep = reinterpret_cast<const float4*>(&enc[b * 512]);
  float s = bih[j];
  for (int d = 0; d < 128; d++) {
    float4 w = wp[d], e = ep[d];
    s += w.x * e.x + w.y * e.y + w.z * e.z + w.w * e.w;
  }
  gx[g] = s;
}

// ---------------- persistent LSTM: local gates, h-broadcast only -----------
// 64 blocks x 256 thr. Block bl owns h-columns [bl*8, bl*8+8) for all 8
// batches; computes the {i,f,g,o} gate rows for those columns locally, so
// only h (4096 floats) is exchanged per step. Parity double-buffered hglob
// + flag-array barrier (contention-free).
__global__ __launch_bounds__(256) void k_lstm3(
    const float* __restrict__ gx, const float* __restrict__ whh,
    const float* __restrict__ bhh, const float* __restrict__ ow,
    const float* __restrict__ ob, float* __restrict__ out,
    float* __restrict__ hglob, unsigned* __restrict__ flags) {
  const int bl = blockIdx.x, tid = threadIdx.x;
  const int part = tid >> 5, idx = tid & 31;       // part: 64-chunk of k
  const int gtype = idx >> 3, ml = idx & 7;
  const int j = gtype * 512 + bl * 8 + ml;          // owned gate row
  __shared__ float h_s[4096];                       // [b][512]
  __shared__ float red[8][32][8];                   // [part][idx][b]
  __shared__ float gvs[8][32];                      // [b][idx]
  __shared__ float ow_s[512];
  __shared__ float ored[4];
  float w[64];
  {
    const float* wr = &whh[(size_t)j * 512 + part * 64];
#pragma unroll
    for (int r = 0; r < 64; r += 4) {
      float4 v = *(const float4*)&wr[r];
      w[r] = v.x; w[r + 1] = v.y; w[r + 2] = v.z; w[r + 3] = v.w;
    }
  }
  const float gxrow = gx[part * 2048 + j] + bhh[j];  // (b=part, row j)
  float cst = 0.f;                                    // live on tid<64
  for (int i = tid; i < 4096; i += 256) h_s[i] = 0.f;
  for (int i = tid; i < 512; i += 256) ow_s[i] = ow[i];
  const float obv = ob[0];
  __syncthreads();
  for (int t = 0; t < TPRED; t++) {
    // partial matvec: 64-chunk dot of row j against h for all 8 batches
    float p[8];
#pragma unroll
    for (int b = 0; b < 8; b++) p[b] = 0.f;
#pragma unroll 4
    for (int r = 0; r < 64; r += 4) {
      float w0 = w[r], w1 = w[r + 1], w2 = w[r + 2], w3 = w[r + 3];
#pragma unroll
      for (int b = 0; b < 8; b++) {
        float4 hv = *(const float4*)&h_s[b * 512 + part * 64 + r];
        p[b] = fmaf(w3, hv.w, fmaf(w2, hv.z, fmaf(w1, hv.y, fmaf(w0, hv.x, p[b]))));
      }
    }
#pragma unroll
    for (int b = 0; b < 8; b++) red[part][idx][b] = p[b];
    __syncthreads();
    float gv = gxrow;                                 // identity: (b=part, row idx)
#pragma unroll
    for (int pp = 0; pp < 8; pp++) gv += red[pp][idx][part];
    gvs[part][idx] = gv;                              // [b][idx]
    __syncthreads();
    float* hgb = hglob + ((t + 1) & 1) * 4096;        // parity buffer
    // local h for owned columns: threads 0..63 -> (b, ml)
    if (tid < 64) {
      int b = tid >> 3, m = tid & 7;
      float gi = gvs[b][m], gf = gvs[b][8 + m];
      float gg = gvs[b][16 + m], go = gvs[b][24 + m];
      float c = sigm(gf) * cst + sigm(gi) * tanhf(gg);
      cst = c;
      float hn = sigm(go) * tanhf(c);
      hgb[b * 512 + bl * 8 + m] = hn;
    }
    __threadfence();
    __syncthreads();
    if (tid == 0)
      __hip_atomic_store(&flags[bl], (unsigned)(t + 1), __ATOMIC_RELEASE,
                         __HIP_MEMORY_SCOPE_AGENT);
    if (tid < 64) {
      unsigned got;
      do {
        got = __hip_atomic_load(&flags[tid], __ATOMIC_ACQUIRE,
                                __HIP_MEMORY_SCOPE_AGENT);
      } while (got < (unsigned)(t + 1));
    }
    __syncthreads();
    for (int i = tid; i < 4096; i += 256)
      h_s[i] = __hip_atomic_load(&hgb[i], __ATOMIC_RELAXED,
                                 __HIP_MEMORY_SCOPE_AGENT);
    __syncthreads();
    if (bl < 8) {                                     // output dot for batch bl
      float s = h_s[bl * 512 + tid] * ow_s[tid] +
                h_s[bl * 512 + 256 + tid] * ow_s[256 + tid];
#pragma unroll
      for (int o = 32; o > 0; o >>= 1) s += __shfl_xor(s, o);
      if ((tid & 63) == 0) ored[tid >> 6] = s;
      __syncthreads();
      if (tid == 0)
        out[bl * TPRED + t] = (ored[0] + ored[1]) + (ored[2] + ored[3]) + obv;
    }
  }
}

// ---------------------------------------------------------------------------
extern "C" void kernel_launch(void* const* d_in, const int* in_sizes, int n_in,
                              void* d_out, int out_size, void* d_ws, size_t ws_size,
                              hipStream_t stream) {
  const float* x = (const float*)d_in[0];
  const int* idx1 = (const int*)d_in[1];
  const int* idx2 = (const int*)d_in[2];
  const float* emb_w = (const float*)d_in[3];
  const float* emb_b = (const float*)d_in[4];
  const float* wq = (const float*)d_in[5];
  const float* bq = (const float*)d_in[6];
  const float* wk = (const float*)d_in[7];
  const float* bk = (const float*)d_in[8];
  const float* wv = (const float*)d_in[9];
  const float* bv = (const float*)d_in[10];
  const float* wo = (const float*)d_in[11];
  const float* bo = (const float*)d_in[12];
  const float* w1 = (const float*)d_in[13];
  const float* b1 = (const float*)d_in[14];
  const float* w2 = (const float*)d_in[15];
  const float* b2 = (const float*)d_in[16];
  const float* ln1g = (const float*)d_in[17];
  const float* ln1b = (const float*)d_in[18];
  const float* ln2g = (const float*)d_in[19];
  const float* ln2b = (const float*)d_in[20];
  const float* conv_w = (const float*)d_in[21];
  const float* conv_b = (const float*)d_in[22];
  const float* bn_g = (const float*)d_in[23];
  const float* bn_b = (const float*)d_in[24];
  const float* bn_m = (const float*)d_in[25];
  const float* bn_v = (const float*)d_in[26];
  const float* lstm_wih = (const float*)d_in[27];
  const float* lstm_whh = (const float*)d_in[28];
  const float* lstm_bih = (const float*)d_in[29];
  const float* lstm_bhh = (const float*)d_in[30];
  const float* out_w = (const float*)d_in[31];
  const float* out_b = (const float*)d_in[32];
  float* outp = (float*)d_out;

  char* ws = (char*)d_ws;
  const size_t MB = 1 << 20;
  float* S0 = (float*)(ws);
  float* S1 = (float*)(ws + 32 * MB);
  float* S2 = (float*)(ws + 64 * MB);
  float* S3 = (float*)(ws + 96 * MB);
  u16* P0 = (u16*)(ws + 128 * MB);
  u16* P1 = (u16*)(ws + 144 * MB);
  u16* P2 = (u16*)(ws + 160 * MB);
  u16* P3 = (u16*)(ws + 176 * MB);
  u16* WATT = (u16*)(ws + 192 * MB);
  u16* W1T = (u16*)(ws + 200 * MB);
  u16* W2T = (u16*)(ws + 208 * MB);
  u16* CWT = (u16*)(ws + 216 * MB);
  char* SMB = ws + 220 * MB;
  float* Mbuf = (float*)(SMB);                       // 512 KB
  float* csp = (float*)(SMB + 512 * 1024);           // 512 KB
  u16* vmh = (u16*)(SMB + 1040 * 1024);
  u16* vml = (u16*)(SMB + 1048 * 1024);
  int* mtop = (int*)(SMB + 1056 * 1024);
  float* gxb = (float*)(SMB + 1088 * 1024);          // 64 KB
  float* encb = (float*)(SMB + 1152 * 1024);
  float* hglob = (float*)(SMB + 1168 * 1024);        // 32 KB (2x4096 floats)
  unsigned* flags = (unsigned*)(SMB + 1216 * 1024);

  auto wat = [&](int l, int m, int hl) {
    return WATT + ((size_t)((l * 4 + m) * 2 + hl)) * 262144;
  };

  // fused weight split (single dispatch)
  {
    dim3 g(4096, 13);
    k_splitall<<<g, 256, 0, stream>>>(wq, wk, wv, wo, w1, w2, conv_w,
                                      WATT, W1T, W2T, CWT);
  }

  auto mg = [&](const u16* Ah, const u16* Al, const u16* Bh, const u16* Bl,
                const float* bias, float* C, int M, int N, int K) {
    dim3 g(N / 128, M / 128);
    k_mgemm<0, 0, 0><<<g, 256, 0, stream>>>(Ah, Al, Bh, Bl, bias, C, nullptr, nullptr,
                                            M, N, K, 0, nullptr, nullptr, nullptr, nullptr);
  };

  // ---------------- embed ----------------
  k_embed<<<BATCH * LL1, 256, 0, stream>>>(x, emb_w, emb_b, S0, P0, P1);

  // ---------------- encoder layer 1 (L=2048, u=40) ----------------
  {
    const int Lc = LL1, u = 40, M = BATCH * LL1;
    mg(P0, P1, wat(0, 0, 0), wat(0, 0, 1), bq, S1, M, 512, 512);
    mg(P0, P1, wat(0, 1, 0), wat(0, 1, 1), bk, S2, M, 512, 512);
    mg(P0, P1, wat(0, 2, 0), wat(0, 2, 1), bv, S3, M, 512, 512);
    k_qk_m<<<M, 320, 0, stream>>>(S1, S2, idx1, Mbuf, Lc, u);
    k_topk<<<64, 256, 0, stream>>>(Mbuf, mtop, Lc, u);
    k_colsum1<<<dim3(BATCH, 32), 512, 0, stream>>>(S3, csp, Lc, Lc / 32);
    k_colsum2<<<BATCH, 512, 0, stream>>>(csp, nullptr, vmh, vml, 32, 1.f / Lc);
    k_ctx_fillb<<<(BATCH * Lc * 128) / 256, 256, 0, stream>>>(P2, P3, vmh, vml, Lc);
    k_attn_mq<<<64 * 8, 256, 0, stream>>>(S1, S2, S3, mtop, P2, P3, Lc, u, 8);
    mg(P2, P3, wat(0, 3, 0), wat(0, 3, 1), bo, S1, M, 512, 512);
    k_add_ln<<<M, 256, 0, stream>>>(S0, S1, ln1g, ln1b, S2, P0, P1);
    u16* hidh = (u16*)S0;
    u16* hidl = (u16*)S1;
    for (int c = 0; c < 2; c++) {
      dim3 g1(16, 64);
      k_mgemm<1, 0, 1><<<g1, 256, 0, stream>>>(
          P0 + (size_t)c * 8192 * 512, P1 + (size_t)c * 8192 * 512,
          W1T, W1T + 1048576, b1, nullptr, hidh, hidl, 8192, 2048, 512, 0,
          nullptr, nullptr, nullptr, nullptr);
      dim3 g2(4, 64);
      k_mgemm<0, 0, 0><<<g2, 256, 0, stream>>>(
          hidh, hidl, W2T, W2T + 1048576, b2, S3 + (size_t)c * 8192 * 512,
          nullptr, nullptr, 8192, 512, 2048, 0, nullptr, nullptr, nullptr, nullptr);
    }
    k_add_ln<<<M, 256, 0, stream>>>(S2, S3, ln2g, ln2b, nullptr, P0, P1);
  }

  // ---------------- conv distill ----------------
  {
    dim3 g(4, 128);
    k_mgemm<2, 1, 0><<<g, 256, 0, stream>>>(P0, P1, CWT, CWT + 786432, conv_b,
                                            S1, nullptr, nullptr, 16384, 512, 1536,
                                            LL1, bn_m, bn_v, bn_g, bn_b);
    k_pool<<<(BATCH * LL2 * 512) / 256, 256, 0, stream>>>(S1, S2, P0, P1);
  }

  // ---------------- encoder layer 2 (L=1024, u=35) ----------------
  {
    const int Lc = LL2, u = 35, M = BATCH * LL2;
    float* Qb = S1;
    float* Kb = S1 + 4194304;
    float* Vb = S3;
    float* AOb = S3 + 4194304;
    mg(P0, P1, wat(1, 0, 0), wat(1, 0, 1), bq + 512, Qb, M, 512, 512);
    mg(P0, P1, wat(1, 1, 0), wat(1, 1, 1), bk + 512, Kb, M, 512, 512);
    mg(P0, P1, wat(1, 2, 0), wat(1, 2, 1), bv + 512, Vb, M, 512, 512);
    k_qk_m<<<M, 320, 0, stream>>>(Qb, Kb, idx2, Mbuf, Lc, u);
    k_topk<<<64, 256, 0, stream>>>(Mbuf, mtop, Lc, u);
    k_colsum1<<<dim3(BATCH, 32), 512, 0, stream>>>(Vb, csp, Lc, Lc / 32);
    k_colsum2<<<BATCH, 512, 0, stream>>>(csp, nullptr, vmh, vml, 32, 1.f / Lc);
    k_ctx_fillb<<<(BATCH * Lc * 128) / 256, 256, 0, stream>>>(P2, P3, vmh, vml, Lc);
    k_attn_mq<<<64 * 7, 256, 0, stream>>>(Qb, Kb, Vb, mtop, P2, P3, Lc, u, 7);
    mg(P2, P3, wat(1, 3, 0), wat(1, 3, 1), bo + 512, AOb, M, 512, 512);
    k_add_ln<<<M, 256, 0, stream>>>(S2, AOb, ln1g + 512, ln1b + 512, S0, P0, P1);
    u16* hidh = (u16*)S1;
    u16* hidl = (u16*)S3;
    {
      dim3 g1(16, 64);
      k_mgemm<1, 0, 1><<<g1, 256, 0, stream>>>(
          P0, P1, W1T + (size_t)2 * 1048576, W1T + (size_t)3 * 1048576, b1 + 2048,
          nullptr, hidh, hidl, 8192, 2048, 512, 0, nullptr, nullptr, nullptr, nullptr);
      dim3 g2(4, 64);
      k_mgemm<0, 0, 0><<<g2, 256, 0, stream>>>(
          hidh, hidl, W2T + (size_t)2 * 1048576, W2T + (size_t)3 * 1048576, b2 + 512,
          S2, nullptr, nullptr, 8192, 512, 2048, 0, nullptr, nullptr, nullptr, nullptr);
    }
    k_add_ln<<<M, 256, 0, stream>>>(S0, S2, ln2g + 512, ln2b + 512, S3, nullptr, nullptr);
  }

  // ---------------- mean -> LSTM -> output ----------------
  k_colsum1<<<dim3(BATCH, 32), 512, 0, stream>>>(S3, csp, LL2, LL2 / 32);
  k_colsum2<<<BATCH, 512, 0, stream>>>(csp, encb, nullptr, nullptr, 32, 1.f / LL2);
  k_gx<<<(BATCH * 2048) / 256, 256, 0, stream>>>(encb, lstm_wih, lstm_bih, gxb, flags);
  k_lstm3<<<64, 256, 0, stream>>>(gxb, lstm_whh, lstm_bhh, out_w, out_b, outp,
                                  hglob, flags);
}

// Round 5
// 2989.562 us; speedup vs baseline: 3.2162x; 1.2453x over previous
//
#include <hip/hip_runtime.h>
#include <hip/hip_bf16.h>
#include <math.h>

static constexpr int BATCH = 8;
static constexpr int LL1 = 2048;
static constexpr int LL2 = 1024;
static constexpr int DMODEL = 512;
static constexpr int NHEADS = 8;
static constexpr int DKH = 64;
static constexpr int TPRED = 100;

typedef unsigned short u16;
typedef unsigned int u32;
typedef unsigned long long u64;
typedef __attribute__((ext_vector_type(8))) short short8;   // 8 bf16
typedef __attribute__((ext_vector_type(4))) float f32x4;

__device__ __forceinline__ float sigm(float x) { return 1.0f / (1.0f + expf(-x)); }

// bf16 split helpers (round-to-nearest-even)
__device__ __forceinline__ u16 f2b(float f) {
  u32 u = __builtin_bit_cast(u32, f);
  return (u16)((u + 0x7fffu + ((u >> 16) & 1u)) >> 16);
}
__device__ __forceinline__ float b2f(u16 h) {
  return __builtin_bit_cast(float, (u32)h << 16);
}

#define GLD16(gsrc, ldst) __builtin_amdgcn_global_load_lds( \
    (const __attribute__((address_space(1))) u32*)(gsrc),   \
    (__attribute__((address_space(3))) u32*)(ldst), 16, 0, 0)

// ---------------- embedding + posenc, writes fp32 + bf16-split -------------
__global__ void k_embed(const float* __restrict__ x, const float* __restrict__ ew,
                        const float* __restrict__ eb, float* __restrict__ out,
                        u16* __restrict__ oh, u16* __restrict__ ol) {
  int row = blockIdx.x;
  int l = row & (LL1 - 1);
  int tid = threadIdx.x;
  __shared__ float xr[64];
  if (tid < 64) xr[tid] = x[row * 64 + tid];
  __syncthreads();
  const float fac = -9.210340371976184f / 512.0f;
  for (int c = tid; c < DMODEL; c += 256) {
    float acc = eb[c];
#pragma unroll 8
    for (int i = 0; i < 64; i++) acc = fmaf(xr[i], ew[i * DMODEL + c], acc);
    float divv = expf((float)(2 * (c >> 1)) * fac);
    float ang = (float)l * divv;
    acc += (c & 1) ? cosf(ang) : sinf(ang);
    size_t o = (size_t)row * DMODEL + c;
    out[o] = acc;
    u16 hh = f2b(acc);
    oh[o] = hh;
    ol[o] = f2b(acc - b2f(hh));
  }
}

// ---------------- MFMA GEMM, bf16x2 split, C = A@B + bias ------------------
template <int EPI, int CONV, int OSPLIT>
__global__ __launch_bounds__(256) void k_mgemm(
    const u16* __restrict__ Ah, const u16* __restrict__ Al,
    const u16* __restrict__ Bh, const u16* __restrict__ Bl,
    const float* __restrict__ bias,
    float* __restrict__ C, u16* __restrict__ Ch, u16* __restrict__ Cl,
    int M, int N, int K, int Lc,
    const float* __restrict__ p_m, const float* __restrict__ p_v,
    const float* __restrict__ p_g, const float* __restrict__ p_b) {
  __shared__ __align__(16) u16 As_h[4096], As_l[4096], Bs_h[4096], Bs_l[4096];
  const int tid = threadIdx.x;
  const int m0 = blockIdx.y * 128, n0 = blockIdx.x * 128;
  const int wid = tid >> 6, lane = tid & 63;
  const int wm = (wid & 1) * 64, wn = (wid >> 1) * 64;
  const int lr = lane >> 4, lc = lane & 15;
  f32x4 acc[4][4];
  f32x4 zz = {0.f, 0.f, 0.f, 0.f};
#pragma unroll
  for (int i = 0; i < 4; i++)
#pragma unroll
    for (int j = 0; j < 4; j++) acc[i][j] = zz;

  for (int k0 = 0; k0 < K; k0 += 32) {
#pragma unroll
    for (int pass = 0; pass < 2; pass++) {
      int c = tid + pass * 256;
      int mi = c >> 2, kc = (c & 3) * 8;
      size_t asrc;
      if (CONV) {
        int m = m0 + mi;
        int b = m >> 11, t = m & (LL1 - 1);      // Lc == LL1 (pow2)
        int kblk = k0 >> 9;
        int srow = (b << 11) + ((t + kblk - 1 + LL1) & (LL1 - 1));
        asrc = (size_t)srow * 512 + (k0 - (kblk << 9)) + kc;
      } else {
        asrc = (size_t)(m0 + mi) * K + k0 + kc;
      }
      size_t bsrc = (size_t)(n0 + mi) * K + k0 + kc;
      u32 ldo = (u32)((wid * 64 + pass * 256) * 8);
      GLD16(Ah + asrc, As_h + ldo);
      GLD16(Al + asrc, As_l + ldo);
      GLD16(Bh + bsrc, Bs_h + ldo);
      GLD16(Bl + bsrc, Bs_l + ldo);
    }
    __syncthreads();
    short8 ah[4], alv[4], bh[4], blv[4];
#pragma unroll
    for (int i = 0; i < 4; i++) {
      int ar = (wm + i * 16 + lc) * 32 + lr * 8;
      int br = (wn + i * 16 + lc) * 32 + lr * 8;
      ah[i] = *(const short8*)&As_h[ar];
      alv[i] = *(const short8*)&As_l[ar];
      bh[i] = *(const short8*)&Bs_h[br];
      blv[i] = *(const short8*)&Bs_l[br];
    }
#pragma unroll
    for (int i = 0; i < 4; i++)
#pragma unroll
      for (int j = 0; j < 4; j++) {
        acc[i][j] = __builtin_amdgcn_mfma_f32_16x16x32_bf16(ah[i], bh[j], acc[i][j], 0, 0, 0);
        acc[i][j] = __builtin_amdgcn_mfma_f32_16x16x32_bf16(ah[i], blv[j], acc[i][j], 0, 0, 0);
        acc[i][j] = __builtin_amdgcn_mfma_f32_16x16x32_bf16(alv[i], bh[j], acc[i][j], 0, 0, 0);
      }
    __syncthreads();
  }
#pragma unroll
  for (int j = 0; j < 4; j++) {
    int col = n0 + wn + j * 16 + lc;
    float bs = bias[col];
    float bnA = 0.f, bnB = 0.f;
    if (EPI == 2) {
      bnA = rsqrtf(p_v[col] + 1e-5f) * p_g[col];
      bnB = p_b[col] - p_m[col] * bnA;
    }
#pragma unroll
    for (int i = 0; i < 4; i++) {
#pragma unroll
      for (int q = 0; q < 4; q++) {
        int row = m0 + wm + i * 16 + lr * 4 + q;
        float t = acc[i][j][q] + bs;
        if (EPI == 1) t = 0.5f * t * (1.0f + erff(t * 0.7071067811865475f));
        if (EPI == 2) { t = t * bnA + bnB; t = t > 0.f ? t : expm1f(t); }
        size_t o = (size_t)row * N + col;
        if (OSPLIT) {
          u16 hh = f2b(t);
          Ch[o] = hh;
          Cl[o] = f2b(t - b2f(hh));
        } else {
          C[o] = t;
        }
      }
    }
  }
}

// ---------------- fused weight split/transpose (all weights, 1 dispatch) ---
__global__ void k_splitall(const float* __restrict__ wq, const float* __restrict__ wk,
                           const float* __restrict__ wv, const float* __restrict__ wo,
                           const float* __restrict__ w1, const float* __restrict__ w2,
                           const float* __restrict__ cw,
                           u16* __restrict__ WATT, u16* __restrict__ W1T,
                           u16* __restrict__ W2T, u16* __restrict__ CWT) {
  int job = blockIdx.y;
  int g = blockIdx.x * 256 + threadIdx.x;
  float v;
  u16 *dh, *dl;
  if (job < 8) {
    if (g >= 262144) return;
    int l = job >> 2, mi = job & 3;
    const float* src = (mi == 0 ? wq : mi == 1 ? wk : mi == 2 ? wv : wo) + (size_t)l * 262144;
    int n = g >> 9, k = g & 511;
    v = src[(size_t)k * 512 + n];
    dh = WATT + (size_t)((l * 4 + mi) * 2) * 262144;
    dl = dh + 262144;
  } else if (job == 8 || job == 10) {           // w1: K=512, N=2048
    if (g >= 1048576) return;
    int l = (job == 10);
    int n = g >> 9, k = g & 511;
    v = w1[(size_t)l * 1048576 + (size_t)k * 2048 + n];
    dh = W1T + (size_t)(l * 2) * 1048576;
    dl = dh + 1048576;
  } else if (job == 9 || job == 11) {           // w2: K=2048, N=512
    if (g >= 1048576) return;
    int l = (job == 11);
    int n = g >> 11, k = g & 2047;
    v = w2[(size_t)l * 1048576 + (size_t)k * 512 + n];
    dh = W2T + (size_t)(l * 2) * 1048576;
    dl = dh + 1048576;
  } else {                                       // conv
    if (g >= 786432) return;
    int c = g / 1536, k = g - c * 1536;
    int kblk = k >> 9, ci = k & 511;
    v = cw[c * 1536 + ci * 3 + kblk];
    dh = CWT;
    dl = CWT + 786432;
  }
  u16 hh = f2b(v);
  dh[g] = hh;
  dl[g] = f2b(v - b2f(hh));
}

// ---------------- sampled qk -> sparsity measure M -------------------------
__global__ void k_qk_m(const float* __restrict__ Q, const float* __restrict__ Km,
                       const int* __restrict__ idx, float* __restrict__ Mout,
                       int Lc, int u) {
  int row = blockIdx.x;
  int b = row / Lc, l = row - b * Lc;
  int tid = threadIdx.x;
  int nt = blockDim.x;
  __shared__ __align__(16) float qlds[DMODEL];
  __shared__ int ilds[40];
  __shared__ float qk[320];
  for (int i = tid; i < DMODEL; i += nt) qlds[i] = Q[(size_t)row * DMODEL + i];
  for (int i = tid; i < u; i += nt) ilds[i] = idx[l * u + i];
  __syncthreads();
  int tot = NHEADS * u;
  if (tid < tot) {
    int j = tid >> 3, h = tid & 7;
    int key = ilds[j];
    const float4* kp = reinterpret_cast<const float4*>(&Km[((size_t)b * Lc + key) * DMODEL + h * DKH]);
    const float4* qp = reinterpret_cast<const float4*>(&qlds[h * DKH]);
    float s = 0.f;
#pragma unroll
    for (int d = 0; d < 16; d++) {
      float4 kv = kp[d], qv = qp[d];
      s += qv.x * kv.x + qv.y * kv.y + qv.z * kv.z + qv.w * kv.w;
    }
    qk[tid] = s;
  }
  __syncthreads();
  if (tid < NHEADS) {
    int h = tid;
    float mx = -INFINITY, sm = 0.f;
    for (int j = 0; j < u; j++) {
      float v = qk[(j << 3) + h];
      mx = fmaxf(mx, v);
      sm += v;
    }
    Mout[((size_t)b * NHEADS + h) * Lc + l] = mx - sm / (float)Lc;
  }
}

// ---------------- top-u via packed u64 keys + wave shuffles ----------------
__global__ void k_topk(const float* __restrict__ Mv, int* __restrict__ mtop,
                       int Lc, int u) {
  int bh = blockIdx.x;
  int tid = threadIdx.x;
  int lane = tid & 63, wv = tid >> 6;
  __shared__ float vals[2048];
  __shared__ u64 wred[4];
  for (int i = tid; i < Lc; i += 256) vals[i] = Mv[(size_t)bh * Lc + i];
  __syncthreads();
  for (int it = 0; it < u; it++) {
    u64 best = 0;
    for (int i = tid; i < Lc; i += 256) {
      u32 ub = __builtin_bit_cast(u32, vals[i]);
      ub = (ub & 0x80000000u) ? ~ub : (ub | 0x80000000u);
      u64 key = ((u64)ub << 32) | (u64)(0xFFFFFFFFu - (u32)i);   // lower idx wins ties
      best = best > key ? best : key;
    }
#pragma unroll
    for (int o = 32; o > 0; o >>= 1) {
      u64 other = __shfl_xor(best, o);
      best = best > other ? best : other;
    }
    if (lane == 0) wred[wv] = best;
    __syncthreads();
    u64 b01 = wred[0] > wred[1] ? wred[0] : wred[1];
    u64 b23 = wred[2] > wred[3] ? wred[2] : wred[3];
    u64 b0 = b01 > b23 ? b01 : b23;
    int bi = (int)(0xFFFFFFFFu - (u32)(b0 & 0xFFFFFFFFu));
    if (tid == 0) {
      mtop[bh * u + it] = bi;
      vals[bi] = -INFINITY;
    }
    __syncthreads();
  }
}

// ---------------- column-sum two-phase -------------------------------------
__global__ void k_colsum1(const float* __restrict__ src, float* __restrict__ part,
                          int Lc, int rp) {
  int b = blockIdx.x, ch = blockIdx.y, c = threadIdx.x;
  const float* p = src + ((size_t)b * Lc + (size_t)ch * rp) * 512 + c;
  float s = 0.f;
  for (int r = 0; r < rp; r++) s += p[(size_t)r * 512];
  part[((b << 5) + ch) * 512 + c] = s;
}
__global__ void k_colsum2(const float* __restrict__ part, float* __restrict__ of,
                          u16* __restrict__ oh, u16* __restrict__ ol,
                          int nch, float scale) {
  int b = blockIdx.x, c = threadIdx.x;
  float s = 0.f;
  for (int i = 0; i < nch; i++) s += part[(b * nch + i) * 512 + c];
  s *= scale;
  if (of) of[b * 512 + c] = s;
  if (oh) {
    u16 hh = f2b(s);
    oh[b * 512 + c] = hh;
    ol[b * 512 + c] = f2b(s - b2f(hh));
  }
}

// ---------------- fill context (bf16-split) with V-mean --------------------
__global__ void k_ctx_fillb(u16* __restrict__ ch, u16* __restrict__ cl,
                            const u16* __restrict__ vh, const u16* __restrict__ vl,
                            int Lc) {
  int g = blockIdx.x * 256 + threadIdx.x;
  int total = BATCH * Lc * 128;
  if (g >= total) return;
  int c4 = g & 127;
  int row = g >> 7;
  int b = row / Lc;
  ((ushort4*)ch)[g] = ((const ushort4*)vh)[b * 128 + c4];
  ((ushort4*)cl)[g] = ((const ushort4*)vl)[b * 128 + c4];
}

// ---------------- attention: 5 queries per block + scatter -----------------
__global__ __launch_bounds__(256) void k_attn_mq(
    const float* __restrict__ Q, const float* __restrict__ Km,
    const float* __restrict__ V, const int* __restrict__ mtop,
    u16* __restrict__ ctxh, u16* __restrict__ ctxl, int Lc, int u, int nqb) {
  int blk = blockIdx.x;
  int qb = blk % nqb;
  int bh = blk / nqb;
  int h = bh & 7, b = bh >> 3;
  int tid = threadIdx.x;
  int lane = tid & 63, wv = tid >> 6;
  __shared__ __align__(16) float qlds[5][64];
  __shared__ float s_lds[5][2048];
  __shared__ float wredA[4], wredB[4];
  __shared__ int rows_s[5];
  __shared__ float part[4][5][64];
  // load 5 query vectors (strided: 320 elements with 256 threads)
  for (int qq = tid; qq < 320; qq += 256) {
    int q = qq >> 6, d = qq & 63;
    int row = mtop[(b * 8 + h) * u + qb * 5 + q];
    if (d == 0) rows_s[q] = row;
    qlds[q][d] = Q[((size_t)b * Lc + row) * DMODEL + h * DKH + d];
  }
  __syncthreads();
  // scores: K row reused across the 5 queries
  for (int k = tid; k < Lc; k += 256) {
    const float4* kp = reinterpret_cast<const float4*>(&Km[((size_t)b * Lc + k) * DMODEL + h * DKH]);
    float s0 = 0, s1 = 0, s2 = 0, s3 = 0, s4 = 0;
#pragma unroll
    for (int d = 0; d < 16; d++) {
      float4 kv = kp[d];
      float4 q0 = ((const float4*)qlds[0])[d];
      float4 q1 = ((const float4*)qlds[1])[d];
      float4 q2 = ((const float4*)qlds[2])[d];
      float4 q3 = ((const float4*)qlds[3])[d];
      float4 q4 = ((const float4*)qlds[4])[d];
      s0 += q0.x * kv.x + q0.y * kv.y + q0.z * kv.z + q0.w * kv.w;
      s1 += q1.x * kv.x + q1.y * kv.y + q1.z * kv.z + q1.w * kv.w;
      s2 += q2.x * kv.x + q2.y * kv.y + q2.z * kv.z + q2.w * kv.w;
      s3 += q3.x * kv.x + q3.y * kv.y + q3.z * kv.z + q3.w * kv.w;
      s4 += q4.x * kv.x + q4.y * kv.y + q4.z * kv.z + q4.w * kv.w;
    }
    s_lds[0][k] = s0 * 0.125f;
    s_lds[1][k] = s1 * 0.125f;
    s_lds[2][k] = s2 * 0.125f;
    s_lds[3][k] = s3 * 0.125f;
    s_lds[4][k] = s4 * 0.125f;
  }
  __syncthreads();
  float denomv[5];
#pragma unroll
  for (int q = 0; q < 5; q++) {
    float mx = -INFINITY;
    for (int k = tid; k < Lc; k += 256) mx = fmaxf(mx, s_lds[q][k]);
#pragma unroll
    for (int o = 32; o > 0; o >>= 1) mx = fmaxf(mx, __shfl_xor(mx, o));
    if (lane == 0) wredA[wv] = mx;
    __syncthreads();
    mx = fmaxf(fmaxf(wredA[0], wredA[1]), fmaxf(wredA[2], wredA[3]));
    float ls = 0.f;
    for (int k = tid; k < Lc; k += 256) {
      float w = expf(s_lds[q][k] - mx);
      s_lds[q][k] = w;
      ls += w;
    }
#pragma unroll
    for (int o = 32; o > 0; o >>= 1) ls += __shfl_xor(ls, o);
    if (lane == 0) wredB[wv] = ls;
    __syncthreads();
    denomv[q] = (wredB[0] + wredB[1]) + (wredB[2] + wredB[3]);
  }
  // PV: V row reused across queries; 4 k-chunks x 64 dims
  float acc0 = 0, acc1 = 0, acc2 = 0, acc3 = 0, acc4 = 0;
  int chunk = Lc >> 2;
  for (int k = wv * chunk; k < (wv + 1) * chunk; k++) {
    float vvv = V[((size_t)b * Lc + k) * DMODEL + h * DKH + lane];
    acc0 = fmaf(s_lds[0][k], vvv, acc0);
    acc1 = fmaf(s_lds[1][k], vvv, acc1);
    acc2 = fmaf(s_lds[2][k], vvv, acc2);
    acc3 = fmaf(s_lds[3][k], vvv, acc3);
    acc4 = fmaf(s_lds[4][k], vvv, acc4);
  }
  part[wv][0][lane] = acc0;
  part[wv][1][lane] = acc1;
  part[wv][2][lane] = acc2;
  part[wv][3][lane] = acc3;
  part[wv][4][lane] = acc4;
  __syncthreads();
  for (int q = wv; q < 5; q += 4) {
    float tot = ((part[0][q][lane] + part[1][q][lane]) +
                 (part[2][q][lane] + part[3][q][lane])) / denomv[q];
    size_t o = ((size_t)b * Lc + rows_s[q]) * DMODEL + h * DKH + lane;
    u16 hh = f2b(tot);
    ctxh[o] = hh;
    ctxl[o] = f2b(tot - b2f(hh));
  }
}

// ---------------- y = LayerNorm(x+a)*g+b ; optional fp32 / split out -------
__global__ void k_add_ln(const float* __restrict__ x, const float* __restrict__ a,
                         const float* __restrict__ g, const float* __restrict__ be,
                         float* __restrict__ y, u16* __restrict__ yh,
                         u16* __restrict__ yl) {
  int row = blockIdx.x;
  int tid = threadIdx.x;
  __shared__ float red[256];
  float2 xv = reinterpret_cast<const float2*>(x)[(size_t)row * 256 + tid];
  float2 av = reinterpret_cast<const float2*>(a)[(size_t)row * 256 + tid];
  float vx = xv.x + av.x, vy = xv.y + av.y;
  red[tid] = vx + vy;
  __syncthreads();
  for (int s = 128; s > 0; s >>= 1) {
    if (tid < s) red[tid] += red[tid + s];
    __syncthreads();
  }
  float mean = red[0] * (1.0f / 512.0f);
  __syncthreads();
  float dx = vx - mean, dy = vy - mean;
  red[tid] = dx * dx + dy * dy;
  __syncthreads();
  for (int s = 128; s > 0; s >>= 1) {
    if (tid < s) red[tid] += red[tid + s];
    __syncthreads();
  }
  float rstd = rsqrtf(red[0] * (1.0f / 512.0f) + 1e-5f);
  int c = tid * 2;
  float ox = dx * rstd * g[c] + be[c];
  float oy = dy * rstd * g[c + 1] + be[c + 1];
  if (y) {
    float2 o = {ox, oy};
    reinterpret_cast<float2*>(y)[(size_t)row * 256 + tid] = o;
  }
  if (yh) {
    size_t base = (size_t)row * 512 + c;
    u16 h0 = f2b(ox), h1 = f2b(oy);
    yh[base] = h0; yh[base + 1] = h1;
    yl[base] = f2b(ox - b2f(h0));
    yl[base + 1] = f2b(oy - b2f(h1));
  }
}

// ---------------- maxpool k=3 s=2, fp32 + split out ------------------------
__global__ void k_pool(const float* __restrict__ cv, float* __restrict__ out,
                       u16* __restrict__ oh, u16* __restrict__ ol) {
  int g = blockIdx.x * 256 + threadIdx.x;
  int total = BATCH * LL2 * DMODEL;
  if (g >= total) return;
  int c = g & 511;
  int rest = g >> 9;
  int i = rest & (LL2 - 1);
  int b = rest >> 10;
  int t0 = 2 * i - 1;
  float m = -INFINITY;
#pragma unroll
  for (int k = 0; k < 3; k++) {
    int t = t0 + k;
    if (t >= 0 && t < LL1) m = fmaxf(m, cv[((size_t)b * LL1 + t) * DMODEL + c]);
  }
  out[g] = m;
  u16 hh = f2b(m);
  oh[g] = hh;
  ol[g] = f2b(m - b2f(hh));
}

// ---------------- gx = enc @ wih^T + bih (+ zero lstm flags) ---------------
__global__ void k_gx(const float* __restrict__ enc, const float* __restrict__ wih,
                     const float* __restrict__ bih, float* __restrict__ gx,
                     unsigned* __restrict__ flags) {
  int g = blockIdx.x * 256 + threadIdx.x;
  if (g < 64) flags[g] = 0u;
  if (g >= BATCH * 2048) return;
  int b = g >> 11, j = g & 2047;
  const float4* wp = reinterpret_cast<const float4*>(&wih[(size_t)j * 512]);
  const float4* ep = reinterpret_cast<const float4*>(&enc[b * 512]);
  float s = bih[j];
  for (int d = 0; d < 128; d++) {
    float4 w = wp[d], e = ep[d];
    s += w.x * e.x + w.y * e.y + w.z * e.z + w.w * e.w;
  }
  gx[g] = s;
}

// ---------------- persistent LSTM: local gates, h-broadcast only -----------
// 64 blocks x 256 thr. Block bl owns h-columns [bl*8, bl*8+8) for all 8
// batches; computes the {i,f,g,o} gate rows for those columns locally, so
// only h (4096 floats) is exchanged per step. Parity double-buffered hglob.
// All exchanged data moves via write-through agent-scope atomics (sc-flagged,
// no L1/L2 involvement) -> no threadfence/L2-writeback needed. Ordering:
// __syncthreads() drains vmcnt (stores complete at coherent point) before
// the flag store issues.
__global__ __launch_bounds__(256) void k_lstm3(
    const float* __restrict__ gx, const float* __restrict__ whh,
    const float* __restrict__ bhh, const float* __restrict__ ow,
    const float* __restrict__ ob, float* __restrict__ out,
    float* __restrict__ hglob, unsigned* __restrict__ flags) {
  const int bl = blockIdx.x, tid = threadIdx.x;
  const int part = tid >> 5, idx = tid & 31;       // part: 64-chunk of k
  const int gtype = idx >> 3, ml = idx & 7;
  const int j = gtype * 512 + bl * 8 + ml;          // owned gate row
  __shared__ float h_s[4096];                       // [b][512]
  __shared__ float red[8][8][32];                   // [b][part][idx] (conflict-free)
  __shared__ float gvs[8][32];                      // [b][idx]
  __shared__ float ow_s[512];
  __shared__ float ored[4];
  float w[64];                                      // FULLY unrolled -> VGPRs
  {
    const float* wr = &whh[(size_t)j * 512 + part * 64];
#pragma unroll
    for (int r = 0; r < 64; r += 4) {
      float4 v = *(const float4*)&wr[r];
      w[r] = v.x; w[r + 1] = v.y; w[r + 2] = v.z; w[r + 3] = v.w;
    }
  }
  const float gxrow = gx[part * 2048 + j] + bhh[j];  // (b=part, row j)
  float cst = 0.f;                                    // live on tid<64
  for (int i = tid; i < 4096; i += 256) h_s[i] = 0.f;
  for (int i = tid; i < 512; i += 256) ow_s[i] = ow[i];
  const float obv = ob[0];
  __syncthreads();
  for (int t = 0; t < TPRED; t++) {
    // partial matvec: 64-chunk dot of row j against h for all 8 batches
    float p[8];
#pragma unroll
    for (int b = 0; b < 8; b++) p[b] = 0.f;
#pragma unroll
    for (int r = 0; r < 64; r += 4) {
      float w0 = w[r], w1 = w[r + 1], w2 = w[r + 2], w3 = w[r + 3];
#pragma unroll
      for (int b = 0; b < 8; b++) {
        float4 hv = *(const float4*)&h_s[b * 512 + part * 64 + r];
        p[b] = fmaf(w3, hv.w, fmaf(w2, hv.z, fmaf(w1, hv.y, fmaf(w0, hv.x, p[b]))));
      }
    }
#pragma unroll
    for (int b = 0; b < 8; b++) red[b][part][idx] = p[b];
    __syncthreads();
    float gv = gxrow;                                 // (b=part, row idx)
#pragma unroll
    for (int pp = 0; pp < 8; pp++) gv += red[part][pp][idx];
    gvs[part][idx] = gv;                              // [b][idx]
    __syncthreads();
    float* hgb = hglob + ((t + 1) & 1) * 4096;        // parity buffer
    // local h for owned columns: threads 0..63 -> (b, ml)
    if (tid < 64) {
      int b = tid >> 3, m = tid & 7;
      float gi = gvs[b][m], gf = gvs[b][8 + m];
      float gg = gvs[b][16 + m], go = gvs[b][24 + m];
      float c = sigm(gf) * cst + sigm(gi) * tanhf(gg);
      cst = c;
      float hn = sigm(go) * tanhf(c);
      __hip_atomic_store(&hgb[b * 512 + bl * 8 + m], hn, __ATOMIC_RELAXED,
                         __HIP_MEMORY_SCOPE_AGENT);
    }
    __syncthreads();   // vmcnt(0) drained: h stores at coherent point
    if (tid == 0)
      __hip_atomic_store(&flags[bl], (unsigned)(t + 1), __ATOMIC_RELAXED,
                         __HIP_MEMORY_SCOPE_AGENT);
    if (tid < 64) {
      while (__hip_atomic_load(&flags[tid], __ATOMIC_RELAXED,
                               __HIP_MEMORY_SCOPE_AGENT) < (unsigned)(t + 1)) {}
    }
    __syncthreads();
    asm volatile("" ::: "memory");
    for (int i = tid; i < 4096; i += 256)
      h_s[i] = __hip_atomic_load(&hgb[i], __ATOMIC_RELAXED,
                                 __HIP_MEMORY_SCOPE_AGENT);
    __syncthreads();
    if (bl < 8) {                                     // output dot for batch bl
      float s = h_s[bl * 512 + tid] * ow_s[tid] +
                h_s[bl * 512 + 256 + tid] * ow_s[256 + tid];
#pragma unroll
      for (int o = 32; o > 0; o >>= 1) s += __shfl_xor(s, o);
      if ((tid & 63) == 0) ored[tid >> 6] = s;
      __syncthreads();
      if (tid == 0)
        out[bl * TPRED + t] = (ored[0] + ored[1]) + (ored[2] + ored[3]) + obv;
    }
  }
}

// ---------------------------------------------------------------------------
extern "C" void kernel_launch(void* const* d_in, const int* in_sizes, int n_in,
                              void* d_out, int out_size, void* d_ws, size_t ws_size,
                              hipStream_t stream) {
  const float* x = (const float*)d_in[0];
  const int* idx1 = (const int*)d_in[1];
  const int* idx2 = (const int*)d_in[2];
  const float* emb_w = (const float*)d_in[3];
  const float* emb_b = (const float*)d_in[4];
  const float* wq = (const float*)d_in[5];
  const float* bq = (const float*)d_in[6];
  const float* wk = (const float*)d_in[7];
  const float* bk = (const float*)d_in[8];
  const float* wv = (const float*)d_in[9];
  const float* bv = (const float*)d_in[10];
  const float* wo = (const float*)d_in[11];
  const float* bo = (const float*)d_in[12];
  const float* w1 = (const float*)d_in[13];
  const float* b1 = (const float*)d_in[14];
  const float* w2 = (const float*)d_in[15];
  const float* b2 = (const float*)d_in[16];
  const float* ln1g = (const float*)d_in[17];
  const float* ln1b = (const float*)d_in[18];
  const float* ln2g = (const float*)d_in[19];
  const float* ln2b = (const float*)d_in[20];
  const float* conv_w = (const float*)d_in[21];
  const float* conv_b = (const float*)d_in[22];
  const float* bn_g = (const float*)d_in[23];
  const float* bn_b = (const float*)d_in[24];
  const float* bn_m = (const float*)d_in[25];
  const float* bn_v = (const float*)d_in[26];
  const float* lstm_wih = (const float*)d_in[27];
  const float* lstm_whh = (const float*)d_in[28];
  const float* lstm_bih = (const float*)d_in[29];
  const float* lstm_bhh = (const float*)d_in[30];
  const float* out_w = (const float*)d_in[31];
  const float* out_b = (const float*)d_in[32];
  float* outp = (float*)d_out;

  char* ws = (char*)d_ws;
  const size_t MB = 1 << 20;
  float* S0 = (float*)(ws);
  float* S1 = (float*)(ws + 32 * MB);
  float* S2 = (float*)(ws + 64 * MB);
  float* S3 = (float*)(ws + 96 * MB);
  u16* P0 = (u16*)(ws + 128 * MB);
  u16* P1 = (u16*)(ws + 144 * MB);
  u16* P2 = (u16*)(ws + 160 * MB);
  u16* P3 = (u16*)(ws + 176 * MB);
  u16* WATT = (u16*)(ws + 192 * MB);
  u16* W1T = (u16*)(ws + 200 * MB);
  u16* W2T = (u16*)(ws + 208 * MB);
  u16* CWT = (u16*)(ws + 216 * MB);
  char* SMB = ws + 220 * MB;
  float* Mbuf = (float*)(SMB);                       // 512 KB
  float* csp = (float*)(SMB + 512 * 1024);           // 512 KB
  u16* vmh = (u16*)(SMB + 1040 * 1024);
  u16* vml = (u16*)(SMB + 1048 * 1024);
  int* mtop = (int*)(SMB + 1056 * 1024);
  float* gxb = (float*)(SMB + 1088 * 1024);          // 64 KB
  float* encb = (float*)(SMB + 1152 * 1024);
  float* hglob = (float*)(SMB + 1168 * 1024);        // 32 KB (2x4096 floats)
  unsigned* flags = (unsigned*)(SMB + 1216 * 1024);

  auto wat = [&](int l, int m, int hl) {
    return WATT + ((size_t)((l * 4 + m) * 2 + hl)) * 262144;
  };

  // fused weight split (single dispatch)
  {
    dim3 g(4096, 13);
    k_splitall<<<g, 256, 0, stream>>>(wq, wk, wv, wo, w1, w2, conv_w,
                                      WATT, W1T, W2T, CWT);
  }

  auto mg = [&](const u16* Ah, const u16* Al, const u16* Bh, const u16* Bl,
                const float* bias, float* C, int M, int N, int K) {
    dim3 g(N / 128, M / 128);
    k_mgemm<0, 0, 0><<<g, 256, 0, stream>>>(Ah, Al, Bh, Bl, bias, C, nullptr, nullptr,
                                            M, N, K, 0, nullptr, nullptr, nullptr, nullptr);
  };

  // ---------------- embed ----------------
  k_embed<<<BATCH * LL1, 256, 0, stream>>>(x, emb_w, emb_b, S0, P0, P1);

  // ---------------- encoder layer 1 (L=2048, u=40) ----------------
  {
    const int Lc = LL1, u = 40, M = BATCH * LL1;
    mg(P0, P1, wat(0, 0, 0), wat(0, 0, 1), bq, S1, M, 512, 512);
    mg(P0, P1, wat(0, 1, 0), wat(0, 1, 1), bk, S2, M, 512, 512);
    mg(P0, P1, wat(0, 2, 0), wat(0, 2, 1), bv, S3, M, 512, 512);
    k_qk_m<<<M, 320, 0, stream>>>(S1, S2, idx1, Mbuf, Lc, u);
    k_topk<<<64, 256, 0, stream>>>(Mbuf, mtop, Lc, u);
    k_colsum1<<<dim3(BATCH, 32), 512, 0, stream>>>(S3, csp, Lc, Lc / 32);
    k_colsum2<<<BATCH, 512, 0, stream>>>(csp, nullptr, vmh, vml, 32, 1.f / Lc);
    k_ctx_fillb<<<(BATCH * Lc * 128) / 256, 256, 0, stream>>>(P2, P3, vmh, vml, Lc);
    k_attn_mq<<<64 * 8, 256, 0, stream>>>(S1, S2, S3, mtop, P2, P3, Lc, u, 8);
    mg(P2, P3, wat(0, 3, 0), wat(0, 3, 1), bo, S1, M, 512, 512);
    k_add_ln<<<M, 256, 0, stream>>>(S0, S1, ln1g, ln1b, S2, P0, P1);
    u16* hidh = (u16*)S0;
    u16* hidl = (u16*)S1;
    for (int c = 0; c < 2; c++) {
      dim3 g1(16, 64);
      k_mgemm<1, 0, 1><<<g1, 256, 0, stream>>>(
          P0 + (size_t)c * 8192 * 512, P1 + (size_t)c * 8192 * 512,
          W1T, W1T + 1048576, b1, nullptr, hidh, hidl, 8192, 2048, 512, 0,
          nullptr, nullptr, nullptr, nullptr);
      dim3 g2(4, 64);
      k_mgemm<0, 0, 0><<<g2, 256, 0, stream>>>(
          hidh, hidl, W2T, W2T + 1048576, b2, S3 + (size_t)c * 8192 * 512,
          nullptr, nullptr, 8192, 512, 2048, 0, nullptr, nullptr, nullptr, nullptr);
    }
    k_add_ln<<<M, 256, 0, stream>>>(S2, S3, ln2g, ln2b, nullptr, P0, P1);
  }

  // ---------------- conv distill ----------------
  {
    dim3 g(4, 128);
    k_mgemm<2, 1, 0><<<g, 256, 0, stream>>>(P0, P1, CWT, CWT + 786432, conv_b,
                                            S1, nullptr, nullptr, 16384, 512, 1536,
                                            LL1, bn_m, bn_v, bn_g, bn_b);
    k_pool<<<(BATCH * LL2 * 512) / 256, 256, 0, stream>>>(S1, S2, P0, P1);
  }

  // ---------------- encoder layer 2 (L=1024, u=35) ----------------
  {
    const int Lc = LL2, u = 35, M = BATCH * LL2;
    float* Qb = S1;
    float* Kb = S1 + 4194304;
    float* Vb = S3;
    float* AOb = S3 + 4194304;
    mg(P0, P1, wat(1, 0, 0), wat(1, 0, 1), bq + 512, Qb, M, 512, 512);
    mg(P0, P1, wat(1, 1, 0), wat(1, 1, 1), bk + 512, Kb, M, 512, 512);
    mg(P0, P1, wat(1, 2, 0), wat(1, 2, 1), bv + 512, Vb, M, 512, 512);
    k_qk_m<<<M, 320, 0, stream>>>(Qb, Kb, idx2, Mbuf, Lc, u);
    k_topk<<<64, 256, 0, stream>>>(Mbuf, mtop, Lc, u);
    k_colsum1<<<dim3(BATCH, 32), 512, 0, stream>>>(Vb, csp, Lc, Lc / 32);
    k_colsum2<<<BATCH, 512, 0, stream>>>(csp, nullptr, vmh, vml, 32, 1.f / Lc);
    k_ctx_fillb<<<(BATCH * Lc * 128) / 256, 256, 0, stream>>>(P2, P3, vmh, vml, Lc);
    k_attn_mq<<<64 * 7, 256, 0, stream>>>(Qb, Kb, Vb, mtop, P2, P3, Lc, u, 7);
    mg(P2, P3, wat(1, 3, 0), wat(1, 3, 1), bo + 512, AOb, M, 512, 512);
    k_add_ln<<<M, 256, 0, stream>>>(S2, AOb, ln1g + 512, ln1b + 512, S0, P0, P1);
    u16* hidh = (u16*)S1;
    u16* hidl = (u16*)S3;
    {
      dim3 g1(16, 64);
      k_mgemm<1, 0, 1><<<g1, 256, 0, stream>>>(
          P0, P1, W1T + (size_t)2 * 1048576, W1T + (size_t)3 * 1048576, b1 + 2048,
          nullptr, hidh, hidl, 8192, 2048, 512, 0, nullptr, nullptr, nullptr, nullptr);
      dim3 g2(4, 64);
      k_mgemm<0, 0, 0><<<g2, 256, 0, stream>>>(
          hidh, hidl, W2T + (size_t)2 * 1048576, W2T + (size_t)3 * 1048576, b2 + 512,
          S2, nullptr, nullptr, 8192, 512, 2048, 0, nullptr, nullptr, nullptr, nullptr);
    }
    k_add_ln<<<M, 256, 0, stream>>>(S0, S2, ln2g + 512, ln2b + 512, S3, nullptr, nullptr);
  }

  // ---------------- mean -> LSTM -> output ----------------
  k_colsum1<<<dim3(BATCH, 32), 512, 0, stream>>>(S3, csp, LL2, LL2 / 32);
  k_colsum2<<<BATCH, 512, 0, stream>>>(csp, encb, nullptr, nullptr, 32, 1.f / LL2);
  k_gx<<<(BATCH * 2048) / 256, 256, 0, stream>>>(encb, lstm_wih, lstm_bih, gxb, flags);
  k_lstm3<<<64, 256, 0, stream>>>(gxb, lstm_whh, lstm_bhh, out_w, out_b, outp,
                                  hglob, flags);
}

// Round 6
// 2619.809 us; speedup vs baseline: 3.6702x; 1.1411x over previous
//
#include <hip/hip_runtime.h>
#include <hip/hip_bf16.h>
#include <math.h>

static constexpr int BATCH = 8;
static constexpr int LL1 = 2048;
static constexpr int LL2 = 1024;
static constexpr int DMODEL = 512;
static constexpr int NHEADS = 8;
static constexpr int DKH = 64;
static constexpr int TPRED = 100;

typedef unsigned short u16;
typedef unsigned int u32;
typedef unsigned long long u64;
typedef __attribute__((ext_vector_type(8))) short short8;   // 8 bf16
typedef __attribute__((ext_vector_type(4))) float f32x4;

__device__ __forceinline__ float sigm(float x) { return 1.0f / (1.0f + expf(-x)); }

// bf16 split helpers (round-to-nearest-even)
__device__ __forceinline__ u16 f2b(float f) {
  u32 u = __builtin_bit_cast(u32, f);
  return (u16)((u + 0x7fffu + ((u >> 16) & 1u)) >> 16);
}
__device__ __forceinline__ float b2f(u16 h) {
  return __builtin_bit_cast(float, (u32)h << 16);
}

#define GLD16(gsrc, ldst) __builtin_amdgcn_global_load_lds( \
    (const __attribute__((address_space(1))) u32*)(gsrc),   \
    (__attribute__((address_space(3))) u32*)(ldst), 16, 0, 0)

// ---------------- embedding + posenc, writes fp32 + bf16-split -------------
__global__ void k_embed(const float* __restrict__ x, const float* __restrict__ ew,
                        const float* __restrict__ eb, float* __restrict__ out,
                        u16* __restrict__ oh, u16* __restrict__ ol) {
  int row = blockIdx.x;
  int l = row & (LL1 - 1);
  int tid = threadIdx.x;
  __shared__ float xr[64];
  if (tid < 64) xr[tid] = x[row * 64 + tid];
  __syncthreads();
  const float fac = -9.210340371976184f / 512.0f;
  for (int c = tid; c < DMODEL; c += 256) {
    float acc = eb[c];
#pragma unroll 8
    for (int i = 0; i < 64; i++) acc = fmaf(xr[i], ew[i * DMODEL + c], acc);
    float divv = expf((float)(2 * (c >> 1)) * fac);
    float ang = (float)l * divv;
    acc += (c & 1) ? cosf(ang) : sinf(ang);
    size_t o = (size_t)row * DMODEL + c;
    out[o] = acc;
    u16 hh = f2b(acc);
    oh[o] = hh;
    ol[o] = f2b(acc - b2f(hh));
  }
}

// ---------------- MFMA GEMM, bf16x2 split, C = A@B + bias ------------------
template <int EPI, int CONV, int OSPLIT>
__global__ __launch_bounds__(256) void k_mgemm(
    const u16* __restrict__ Ah, const u16* __restrict__ Al,
    const u16* __restrict__ Bh, const u16* __restrict__ Bl,
    const float* __restrict__ bias,
    float* __restrict__ C, u16* __restrict__ Ch, u16* __restrict__ Cl,
    int M, int N, int K, int Lc,
    const float* __restrict__ p_m, const float* __restrict__ p_v,
    const float* __restrict__ p_g, const float* __restrict__ p_b) {
  __shared__ __align__(16) u16 As_h[4096], As_l[4096], Bs_h[4096], Bs_l[4096];
  const int tid = threadIdx.x;
  const int m0 = blockIdx.y * 128, n0 = blockIdx.x * 128;
  const int wid = tid >> 6, lane = tid & 63;
  const int wm = (wid & 1) * 64, wn = (wid >> 1) * 64;
  const int lr = lane >> 4, lc = lane & 15;
  f32x4 acc[4][4];
  f32x4 zz = {0.f, 0.f, 0.f, 0.f};
#pragma unroll
  for (int i = 0; i < 4; i++)
#pragma unroll
    for (int j = 0; j < 4; j++) acc[i][j] = zz;

  for (int k0 = 0; k0 < K; k0 += 32) {
#pragma unroll
    for (int pass = 0; pass < 2; pass++) {
      int c = tid + pass * 256;
      int mi = c >> 2, kc = (c & 3) * 8;
      size_t asrc;
      if (CONV) {
        int m = m0 + mi;
        int b = m >> 11, t = m & (LL1 - 1);      // Lc == LL1 (pow2)
        int kblk = k0 >> 9;
        int srow = (b << 11) + ((t + kblk - 1 + LL1) & (LL1 - 1));
        asrc = (size_t)srow * 512 + (k0 - (kblk << 9)) + kc;
      } else {
        asrc = (size_t)(m0 + mi) * K + k0 + kc;
      }
      size_t bsrc = (size_t)(n0 + mi) * K + k0 + kc;
      u32 ldo = (u32)((wid * 64 + pass * 256) * 8);
      GLD16(Ah + asrc, As_h + ldo);
      GLD16(Al + asrc, As_l + ldo);
      GLD16(Bh + bsrc, Bs_h + ldo);
      GLD16(Bl + bsrc, Bs_l + ldo);
    }
    __syncthreads();
    short8 ah[4], alv[4], bh[4], blv[4];
#pragma unroll
    for (int i = 0; i < 4; i++) {
      int ar = (wm + i * 16 + lc) * 32 + lr * 8;
      int br = (wn + i * 16 + lc) * 32 + lr * 8;
      ah[i] = *(const short8*)&As_h[ar];
      alv[i] = *(const short8*)&As_l[ar];
      bh[i] = *(const short8*)&Bs_h[br];
      blv[i] = *(const short8*)&Bs_l[br];
    }
#pragma unroll
    for (int i = 0; i < 4; i++)
#pragma unroll
      for (int j = 0; j < 4; j++) {
        acc[i][j] = __builtin_amdgcn_mfma_f32_16x16x32_bf16(ah[i], bh[j], acc[i][j], 0, 0, 0);
        acc[i][j] = __builtin_amdgcn_mfma_f32_16x16x32_bf16(ah[i], blv[j], acc[i][j], 0, 0, 0);
        acc[i][j] = __builtin_amdgcn_mfma_f32_16x16x32_bf16(alv[i], bh[j], acc[i][j], 0, 0, 0);
      }
    __syncthreads();
  }
#pragma unroll
  for (int j = 0; j < 4; j++) {
    int col = n0 + wn + j * 16 + lc;
    float bs = bias[col];
    float bnA = 0.f, bnB = 0.f;
    if (EPI == 2) {
      bnA = rsqrtf(p_v[col] + 1e-5f) * p_g[col];
      bnB = p_b[col] - p_m[col] * bnA;
    }
#pragma unroll
    for (int i = 0; i < 4; i++) {
#pragma unroll
      for (int q = 0; q < 4; q++) {
        int row = m0 + wm + i * 16 + lr * 4 + q;
        float t = acc[i][j][q] + bs;
        if (EPI == 1) t = 0.5f * t * (1.0f + erff(t * 0.7071067811865475f));
        if (EPI == 2) { t = t * bnA + bnB; t = t > 0.f ? t : expm1f(t); }
        size_t o = (size_t)row * N + col;
        if (OSPLIT) {
          u16 hh = f2b(t);
          Ch[o] = hh;
          Cl[o] = f2b(t - b2f(hh));
        } else {
          C[o] = t;
        }
      }
    }
  }
}

// ---------------- fused weight split/transpose (all weights, 1 dispatch) ---
__global__ void k_splitall(const float* __restrict__ wq, const float* __restrict__ wk,
                           const float* __restrict__ wv, const float* __restrict__ wo,
                           const float* __restrict__ w1, const float* __restrict__ w2,
                           const float* __restrict__ cw,
                           u16* __restrict__ WATT, u16* __restrict__ W1T,
                           u16* __restrict__ W2T, u16* __restrict__ CWT) {
  int job = blockIdx.y;
  int g = blockIdx.x * 256 + threadIdx.x;
  float v;
  u16 *dh, *dl;
  if (job < 8) {
    if (g >= 262144) return;
    int l = job >> 2, mi = job & 3;
    const float* src = (mi == 0 ? wq : mi == 1 ? wk : mi == 2 ? wv : wo) + (size_t)l * 262144;
    int n = g >> 9, k = g & 511;
    v = src[(size_t)k * 512 + n];
    dh = WATT + (size_t)((l * 4 + mi) * 2) * 262144;
    dl = dh + 262144;
  } else if (job == 8 || job == 10) {           // w1: K=512, N=2048
    if (g >= 1048576) return;
    int l = (job == 10);
    int n = g >> 9, k = g & 511;
    v = w1[(size_t)l * 1048576 + (size_t)k * 2048 + n];
    dh = W1T + (size_t)(l * 2) * 1048576;
    dl = dh + 1048576;
  } else if (job == 9 || job == 11) {           // w2: K=2048, N=512
    if (g >= 1048576) return;
    int l = (job == 11);
    int n = g >> 11, k = g & 2047;
    v = w2[(size_t)l * 1048576 + (size_t)k * 512 + n];
    dh = W2T + (size_t)(l * 2) * 1048576;
    dl = dh + 1048576;
  } else {                                       // conv
    if (g >= 786432) return;
    int c = g / 1536, k = g - c * 1536;
    int kblk = k >> 9, ci = k & 511;
    v = cw[c * 1536 + ci * 3 + kblk];
    dh = CWT;
    dl = CWT + 786432;
  }
  u16 hh = f2b(v);
  dh[g] = hh;
  dl[g] = f2b(v - b2f(hh));
}

// ---------------- sampled qk -> sparsity measure M -------------------------
__global__ void k_qk_m(const float* __restrict__ Q, const float* __restrict__ Km,
                       const int* __restrict__ idx, float* __restrict__ Mout,
                       int Lc, int u) {
  int row = blockIdx.x;
  int b = row / Lc, l = row - b * Lc;
  int tid = threadIdx.x;
  int nt = blockDim.x;
  __shared__ __align__(16) float qlds[DMODEL];
  __shared__ int ilds[40];
  __shared__ float qk[320];
  for (int i = tid; i < DMODEL; i += nt) qlds[i] = Q[(size_t)row * DMODEL + i];
  for (int i = tid; i < u; i += nt) ilds[i] = idx[l * u + i];
  __syncthreads();
  int tot = NHEADS * u;
  if (tid < tot) {
    int j = tid >> 3, h = tid & 7;
    int key = ilds[j];
    const float4* kp = reinterpret_cast<const float4*>(&Km[((size_t)b * Lc + key) * DMODEL + h * DKH]);
    const float4* qp = reinterpret_cast<const float4*>(&qlds[h * DKH]);
    float s = 0.f;
#pragma unroll
    for (int d = 0; d < 16; d++) {
      float4 kv = kp[d], qv = qp[d];
      s += qv.x * kv.x + qv.y * kv.y + qv.z * kv.z + qv.w * kv.w;
    }
    qk[tid] = s;
  }
  __syncthreads();
  if (tid < NHEADS) {
    int h = tid;
    float mx = -INFINITY, sm = 0.f;
    for (int j = 0; j < u; j++) {
      float v = qk[(j << 3) + h];
      mx = fmaxf(mx, v);
      sm += v;
    }
    Mout[((size_t)b * NHEADS + h) * Lc + l] = mx - sm / (float)Lc;
  }
}

// ---------------- top-u via packed u64 keys + wave shuffles ----------------
__global__ void k_topk(const float* __restrict__ Mv, int* __restrict__ mtop,
                       int Lc, int u) {
  int bh = blockIdx.x;
  int tid = threadIdx.x;
  int lane = tid & 63, wv = tid >> 6;
  __shared__ float vals[2048];
  __shared__ u64 wred[4];
  for (int i = tid; i < Lc; i += 256) vals[i] = Mv[(size_t)bh * Lc + i];
  __syncthreads();
  for (int it = 0; it < u; it++) {
    u64 best = 0;
    for (int i = tid; i < Lc; i += 256) {
      u32 ub = __builtin_bit_cast(u32, vals[i]);
      ub = (ub & 0x80000000u) ? ~ub : (ub | 0x80000000u);
      u64 key = ((u64)ub << 32) | (u64)(0xFFFFFFFFu - (u32)i);   // lower idx wins ties
      best = best > key ? best : key;
    }
#pragma unroll
    for (int o = 32; o > 0; o >>= 1) {
      u64 other = __shfl_xor(best, o);
      best = best > other ? best : other;
    }
    if (lane == 0) wred[wv] = best;
    __syncthreads();
    u64 b01 = wred[0] > wred[1] ? wred[0] : wred[1];
    u64 b23 = wred[2] > wred[3] ? wred[2] : wred[3];
    u64 b0 = b01 > b23 ? b01 : b23;
    int bi = (int)(0xFFFFFFFFu - (u32)(b0 & 0xFFFFFFFFu));
    if (tid == 0) {
      mtop[bh * u + it] = bi;
      vals[bi] = -INFINITY;
    }
    __syncthreads();
  }
}

// ---------------- column-sum two-phase -------------------------------------
__global__ void k_colsum1(const float* __restrict__ src, float* __restrict__ part,
                          int Lc, int rp) {
  int b = blockIdx.x, ch = blockIdx.y, c = threadIdx.x;
  const float* p = src + ((size_t)b * Lc + (size_t)ch * rp) * 512 + c;
  float s = 0.f;
  for (int r = 0; r < rp; r++) s += p[(size_t)r * 512];
  part[((b << 5) + ch) * 512 + c] = s;
}
__global__ void k_colsum2(const float* __restrict__ part, float* __restrict__ of,
                          u16* __restrict__ oh, u16* __restrict__ ol,
                          int nch, float scale) {
  int b = blockIdx.x, c = threadIdx.x;
  float s = 0.f;
  for (int i = 0; i < nch; i++) s += part[(b * nch + i) * 512 + c];
  s *= scale;
  if (of) of[b * 512 + c] = s;
  if (oh) {
    u16 hh = f2b(s);
    oh[b * 512 + c] = hh;
    ol[b * 512 + c] = f2b(s - b2f(hh));
  }
}

// ---------------- fill context (bf16-split) with V-mean --------------------
__global__ void k_ctx_fillb(u16* __restrict__ ch, u16* __restrict__ cl,
                            const u16* __restrict__ vh, const u16* __restrict__ vl,
                            int Lc) {
  int g = blockIdx.x * 256 + threadIdx.x;
  int total = BATCH * Lc * 128;
  if (g >= total) return;
  int c4 = g & 127;
  int row = g >> 7;
  int b = row / Lc;
  ((ushort4*)ch)[g] = ((const ushort4*)vh)[b * 128 + c4];
  ((ushort4*)cl)[g] = ((const ushort4*)vl)[b * 128 + c4];
}

// ---------------- attention: 5 queries per block + scatter -----------------
__global__ __launch_bounds__(256) void k_attn_mq(
    const float* __restrict__ Q, const float* __restrict__ Km,
    const float* __restrict__ V, const int* __restrict__ mtop,
    u16* __restrict__ ctxh, u16* __restrict__ ctxl, int Lc, int u, int nqb) {
  int blk = blockIdx.x;
  int qb = blk % nqb;
  int bh = blk / nqb;
  int h = bh & 7, b = bh >> 3;
  int tid = threadIdx.x;
  int lane = tid & 63, wv = tid >> 6;
  __shared__ __align__(16) float qlds[5][64];
  __shared__ float s_lds[5][2048];
  __shared__ float wredA[4], wredB[4];
  __shared__ int rows_s[5];
  __shared__ float part[4][5][64];
  // load 5 query vectors (strided: 320 elements with 256 threads)
  for (int qq = tid; qq < 320; qq += 256) {
    int q = qq >> 6, d = qq & 63;
    int row = mtop[(b * 8 + h) * u + qb * 5 + q];
    if (d == 0) rows_s[q] = row;
    qlds[q][d] = Q[((size_t)b * Lc + row) * DMODEL + h * DKH + d];
  }
  __syncthreads();
  // scores: K row reused across the 5 queries
  for (int k = tid; k < Lc; k += 256) {
    const float4* kp = reinterpret_cast<const float4*>(&Km[((size_t)b * Lc + k) * DMODEL + h * DKH]);
    float s0 = 0, s1 = 0, s2 = 0, s3 = 0, s4 = 0;
#pragma unroll
    for (int d = 0; d < 16; d++) {
      float4 kv = kp[d];
      float4 q0 = ((const float4*)qlds[0])[d];
      float4 q1 = ((const float4*)qlds[1])[d];
      float4 q2 = ((const float4*)qlds[2])[d];
      float4 q3 = ((const float4*)qlds[3])[d];
      float4 q4 = ((const float4*)qlds[4])[d];
      s0 += q0.x * kv.x + q0.y * kv.y + q0.z * kv.z + q0.w * kv.w;
      s1 += q1.x * kv.x + q1.y * kv.y + q1.z * kv.z + q1.w * kv.w;
      s2 += q2.x * kv.x + q2.y * kv.y + q2.z * kv.z + q2.w * kv.w;
      s3 += q3.x * kv.x + q3.y * kv.y + q3.z * kv.z + q3.w * kv.w;
      s4 += q4.x * kv.x + q4.y * kv.y + q4.z * kv.z + q4.w * kv.w;
    }
    s_lds[0][k] = s0 * 0.125f;
    s_lds[1][k] = s1 * 0.125f;
    s_lds[2][k] = s2 * 0.125f;
    s_lds[3][k] = s3 * 0.125f;
    s_lds[4][k] = s4 * 0.125f;
  }
  __syncthreads();
  float denomv[5];
#pragma unroll
  for (int q = 0; q < 5; q++) {
    float mx = -INFINITY;
    for (int k = tid; k < Lc; k += 256) mx = fmaxf(mx, s_lds[q][k]);
#pragma unroll
    for (int o = 32; o > 0; o >>= 1) mx = fmaxf(mx, __shfl_xor(mx, o));
    if (lane == 0) wredA[wv] = mx;
    __syncthreads();
    mx = fmaxf(fmaxf(wredA[0], wredA[1]), fmaxf(wredA[2], wredA[3]));
    float ls = 0.f;
    for (int k = tid; k < Lc; k += 256) {
      float w = expf(s_lds[q][k] - mx);
      s_lds[q][k] = w;
      ls += w;
    }
#pragma unroll
    for (int o = 32; o > 0; o >>= 1) ls += __shfl_xor(ls, o);
    if (lane == 0) wredB[wv] = ls;
    __syncthreads();
    denomv[q] = (wredB[0] + wredB[1]) + (wredB[2] + wredB[3]);
  }
  // PV: V row reused across queries; 4 k-chunks x 64 dims
  float acc0 = 0, acc1 = 0, acc2 = 0, acc3 = 0, acc4 = 0;
  int chunk = Lc >> 2;
  for (int k = wv * chunk; k < (wv + 1) * chunk; k++) {
    float vvv = V[((size_t)b * Lc + k) * DMODEL + h * DKH + lane];
    acc0 = fmaf(s_lds[0][k], vvv, acc0);
    acc1 = fmaf(s_lds[1][k], vvv, acc1);
    acc2 = fmaf(s_lds[2][k], vvv, acc2);
    acc3 = fmaf(s_lds[3][k], vvv, acc3);
    acc4 = fmaf(s_lds[4][k], vvv, acc4);
  }
  part[wv][0][lane] = acc0;
  part[wv][1][lane] = acc1;
  part[wv][2][lane] = acc2;
  part[wv][3][lane] = acc3;
  part[wv][4][lane] = acc4;
  __syncthreads();
  for (int q = wv; q < 5; q += 4) {
    float tot = ((part[0][q][lane] + part[1][q][lane]) +
                 (part[2][q][lane] + part[3][q][lane])) / denomv[q];
    size_t o = ((size_t)b * Lc + rows_s[q]) * DMODEL + h * DKH + lane;
    u16 hh = f2b(tot);
    ctxh[o] = hh;
    ctxl[o] = f2b(tot - b2f(hh));
  }
}

// ---------------- y = LayerNorm(x+a)*g+b ; optional fp32 / split out -------
__global__ void k_add_ln(const float* __restrict__ x, const float* __restrict__ a,
                         const float* __restrict__ g, const float* __restrict__ be,
                         float* __restrict__ y, u16* __restrict__ yh,
                         u16* __restrict__ yl) {
  int row = blockIdx.x;
  int tid = threadIdx.x;
  __shared__ float red[256];
  float2 xv = reinterpret_cast<const float2*>(x)[(size_t)row * 256 + tid];
  float2 av = reinterpret_cast<const float2*>(a)[(size_t)row * 256 + tid];
  float vx = xv.x + av.x, vy = xv.y + av.y;
  red[tid] = vx + vy;
  __syncthreads();
  for (int s = 128; s > 0; s >>= 1) {
    if (tid < s) red[tid] += red[tid + s];
    __syncthreads();
  }
  float mean = red[0] * (1.0f / 512.0f);
  __syncthreads();
  float dx = vx - mean, dy = vy - mean;
  red[tid] = dx * dx + dy * dy;
  __syncthreads();
  for (int s = 128; s > 0; s >>= 1) {
    if (tid < s) red[tid] += red[tid + s];
    __syncthreads();
  }
  float rstd = rsqrtf(red[0] * (1.0f / 512.0f) + 1e-5f);
  int c = tid * 2;
  float ox = dx * rstd * g[c] + be[c];
  float oy = dy * rstd * g[c + 1] + be[c + 1];
  if (y) {
    float2 o = {ox, oy};
    reinterpret_cast<float2*>(y)[(size_t)row * 256 + tid] = o;
  }
  if (yh) {
    size_t base = (size_t)row * 512 + c;
    u16 h0 = f2b(ox), h1 = f2b(oy);
    yh[base] = h0; yh[base + 1] = h1;
    yl[base] = f2b(ox - b2f(h0));
    yl[base + 1] = f2b(oy - b2f(h1));
  }
}

// ---------------- maxpool k=3 s=2, fp32 + split out ------------------------
__global__ void k_pool(const float* __restrict__ cv, float* __restrict__ out,
                       u16* __restrict__ oh, u16* __restrict__ ol) {
  int g = blockIdx.x * 256 + threadIdx.x;
  int total = BATCH * LL2 * DMODEL;
  if (g >= total) return;
  int c = g & 511;
  int rest = g >> 9;
  int i = rest & (LL2 - 1);
  int b = rest >> 10;
  int t0 = 2 * i - 1;
  float m = -INFINITY;
#pragma unroll
  for (int k = 0; k < 3; k++) {
    int t = t0 + k;
    if (t >= 0 && t < LL1) m = fmaxf(m, cv[((size_t)b * LL1 + t) * DMODEL + c]);
  }
  out[g] = m;
  u16 hh = f2b(m);
  oh[g] = hh;
  ol[g] = f2b(m - b2f(hh));
}

// ---------------- gx = enc @ wih^T + bih (+ zero lstm flags) ---------------
__global__ void k_gx(const float* __restrict__ enc, const float* __restrict__ wih,
                     const float* __restrict__ bih, float* __restrict__ gx,
                     unsigned* __restrict__ flags) {
  int g = blockIdx.x * 256 + threadIdx.x;
  if (g < 64) flags[g] = 0u;
  if (g >= BATCH * 2048) return;
  int b = g >> 11, j = g & 2047;
  const float4* wp = reinterpret_cast<const float4*>(&wih[(size_t)j * 512]);
  const float4* ep = reinterpret_cast<const float4*>(&enc[b * 512]);
  float s = bih[j];
  for (int d = 0; d < 128; d++) {
    float4 w = wp[d], e = ep[d];
    s += w.x * e.x + w.y * e.y + w.z * e.z + w.w * e.w;
  }
  gx[g] = s;
}

// ---------------- persistent LSTM: local gates, h-broadcast only -----------
// 64 blocks x 256 thr. Block bl owns h-columns [bl*8, bl*8+8) for all 8
// batches; computes the {i,f,g,o} gate rows for those columns locally, so
// only h (4096 floats) is exchanged per step. Parity double-buffered hglob.
// Writes: relaxed agent-scope atomic stores (write-through); __syncthreads()
// drains vmcnt before the flag store. Reads: inline-asm sc0/sc1 dwordx4 loads
// (coherent-point reads, all issued before one vmcnt wait).
__global__ __launch_bounds__(256, 1) void k_lstm3(
    const float* __restrict__ gx, const float* __restrict__ whh,
    const float* __restrict__ bhh, const float* __restrict__ ow,
    const float* __restrict__ ob, float* __restrict__ out,
    float* __restrict__ hglob, unsigned* __restrict__ flags) {
  const int bl = blockIdx.x, tid = threadIdx.x;
  const int part = tid >> 5, idx = tid & 31;       // part: 64-chunk of k
  const int gtype = idx >> 3, ml = idx & 7;
  const int j = gtype * 512 + bl * 8 + ml;          // owned gate row
  __shared__ float h_s[4096];                       // [b][512]
  __shared__ float red[8][8][32];                   // [b][part][idx] (conflict-free)
  __shared__ float gvs[8][32];                      // [b][idx]
  __shared__ float ow_s[512];
  __shared__ float ored[4];
  float w[64];                                      // in VGPRs (launch_bounds 256,1)
  {
    const float* wr = &whh[(size_t)j * 512 + part * 64];
#pragma unroll
    for (int r = 0; r < 64; r += 4) {
      float4 v = *(const float4*)&wr[r];
      w[r] = v.x; w[r + 1] = v.y; w[r + 2] = v.z; w[r + 3] = v.w;
    }
  }
  const float gxrow = gx[part * 2048 + j] + bhh[j];  // (b=part, row j)
  float cst = 0.f;                                    // live on tid<64
  for (int i = tid; i < 4096; i += 256) h_s[i] = 0.f;
  for (int i = tid; i < 512; i += 256) ow_s[i] = ow[i];
  const float obv = ob[0];
  __syncthreads();
  for (int t = 0; t < TPRED; t++) {
    // partial matvec: 64-chunk dot of row j against h for all 8 batches
    float p[8];
#pragma unroll
    for (int b = 0; b < 8; b++) p[b] = 0.f;
#pragma unroll
    for (int r = 0; r < 64; r += 4) {
      float w0 = w[r], w1 = w[r + 1], w2 = w[r + 2], w3 = w[r + 3];
#pragma unroll
      for (int b = 0; b < 8; b++) {
        float4 hv = *(const float4*)&h_s[b * 512 + part * 64 + r];
        p[b] = fmaf(w3, hv.w, fmaf(w2, hv.z, fmaf(w1, hv.y, fmaf(w0, hv.x, p[b]))));
      }
    }
#pragma unroll
    for (int b = 0; b < 8; b++) red[b][part][idx] = p[b];
    __syncthreads();
    float gv = gxrow;                                 // (b=part, row idx)
#pragma unroll
    for (int pp = 0; pp < 8; pp++) gv += red[part][pp][idx];
    gvs[part][idx] = gv;                              // [b][idx]
    __syncthreads();
    float* hgb = hglob + ((t + 1) & 1) * 4096;        // parity buffer
    // local h for owned columns: threads 0..63 -> (b, ml)
    if (tid < 64) {
      int b = tid >> 3, m = tid & 7;
      float gi = gvs[b][m], gf = gvs[b][8 + m];
      float gg = gvs[b][16 + m], go = gvs[b][24 + m];
      float c = sigm(gf) * cst + sigm(gi) * tanhf(gg);
      cst = c;
      float hn = sigm(go) * tanhf(c);
      __hip_atomic_store(&hgb[b * 512 + bl * 8 + m], hn, __ATOMIC_RELAXED,
                         __HIP_MEMORY_SCOPE_AGENT);
    }
    __syncthreads();   // vmcnt(0) drained: h stores at coherent point
    if (tid == 0)
      __hip_atomic_store(&flags[bl], (unsigned)(t + 1), __ATOMIC_RELAXED,
                         __HIP_MEMORY_SCOPE_AGENT);
    if (tid < 64) {
      while (__hip_atomic_load(&flags[tid], __ATOMIC_RELAXED,
                               __HIP_MEMORY_SCOPE_AGENT) < (unsigned)(t + 1)) {}
    }
    __syncthreads();
    asm volatile("" ::: "memory");
    {
      // coherent parallel read of 4 float4 per thread (1024 float4 total)
      const float4* hp = (const float4*)hgb;
      float4 r0, r1, r2, r3;
      asm volatile("global_load_dwordx4 %0, %1, off sc0 sc1"
                   : "=v"(r0) : "v"(hp + tid) : "memory");
      asm volatile("global_load_dwordx4 %0, %1, off sc0 sc1"
                   : "=v"(r1) : "v"(hp + tid + 256) : "memory");
      asm volatile("global_load_dwordx4 %0, %1, off sc0 sc1"
                   : "=v"(r2) : "v"(hp + tid + 512) : "memory");
      asm volatile("global_load_dwordx4 %0, %1, off sc0 sc1"
                   : "=v"(r3) : "v"(hp + tid + 768) : "memory");
      asm volatile("s_waitcnt vmcnt(0)" ::: "memory");
      ((float4*)h_s)[tid] = r0;
      ((float4*)h_s)[tid + 256] = r1;
      ((float4*)h_s)[tid + 512] = r2;
      ((float4*)h_s)[tid + 768] = r3;
    }
    __syncthreads();
    if (bl < 8) {                                     // output dot for batch bl
      float s = h_s[bl * 512 + tid] * ow_s[tid] +
                h_s[bl * 512 + 256 + tid] * ow_s[256 + tid];
#pragma unroll
      for (int o = 32; o > 0; o >>= 1) s += __shfl_xor(s, o);
      if ((tid & 63) == 0) ored[tid >> 6] = s;
      __syncthreads();
      if (tid == 0)
        out[bl * TPRED + t] = (ored[0] + ored[1]) + (ored[2] + ored[3]) + obv;
    }
  }
}

// ---------------------------------------------------------------------------
extern "C" void kernel_launch(void* const* d_in, const int* in_sizes, int n_in,
                              void* d_out, int out_size, void* d_ws, size_t ws_size,
                              hipStream_t stream) {
  const float* x = (const float*)d_in[0];
  const int* idx1 = (const int*)d_in[1];
  const int* idx2 = (const int*)d_in[2];
  const float* emb_w = (const float*)d_in[3];
  const float* emb_b = (const float*)d_in[4];
  const float* wq = (const float*)d_in[5];
  const float* bq = (const float*)d_in[6];
  const float* wk = (const float*)d_in[7];
  const float* bk = (const float*)d_in[8];
  const float* wv = (const float*)d_in[9];
  const float* bv = (const float*)d_in[10];
  const float* wo = (const float*)d_in[11];
  const float* bo = (const float*)d_in[12];
  const float* w1 = (const float*)d_in[13];
  const float* b1 = (const float*)d_in[14];
  const float* w2 = (const float*)d_in[15];
  const float* b2 = (const float*)d_in[16];
  const float* ln1g = (const float*)d_in[17];
  const float* ln1b = (const float*)d_in[18];
  const float* ln2g = (const float*)d_in[19];
  const float* ln2b = (const float*)d_in[20];
  const float* conv_w = (const float*)d_in[21];
  const float* conv_b = (const float*)d_in[22];
  const float* bn_g = (const float*)d_in[23];
  const float* bn_b = (const float*)d_in[24];
  const float* bn_m = (const float*)d_in[25];
  const float* bn_v = (const float*)d_in[26];
  const float* lstm_wih = (const float*)d_in[27];
  const float* lstm_whh = (const float*)d_in[28];
  const float* lstm_bih = (const float*)d_in[29];
  const float* lstm_bhh = (const float*)d_in[30];
  const float* out_w = (const float*)d_in[31];
  const float* out_b = (const float*)d_in[32];
  float* outp = (float*)d_out;

  char* ws = (char*)d_ws;
  const size_t MB = 1 << 20;
  float* S0 = (float*)(ws);
  float* S1 = (float*)(ws + 32 * MB);
  float* S2 = (float*)(ws + 64 * MB);
  float* S3 = (float*)(ws + 96 * MB);
  u16* P0 = (u16*)(ws + 128 * MB);
  u16* P1 = (u16*)(ws + 144 * MB);
  u16* P2 = (u16*)(ws + 160 * MB);
  u16* P3 = (u16*)(ws + 176 * MB);
  u16* WATT = (u16*)(ws + 192 * MB);
  u16* W1T = (u16*)(ws + 200 * MB);
  u16* W2T = (u16*)(ws + 208 * MB);
  u16* CWT = (u16*)(ws + 216 * MB);
  char* SMB = ws + 220 * MB;
  float* Mbuf = (float*)(SMB);                       // 512 KB
  float* csp = (float*)(SMB + 512 * 1024);           // 512 KB
  u16* vmh = (u16*)(SMB + 1040 * 1024);
  u16* vml = (u16*)(SMB + 1048 * 1024);
  int* mtop = (int*)(SMB + 1056 * 1024);
  float* gxb = (float*)(SMB + 1088 * 1024);          // 64 KB
  float* encb = (float*)(SMB + 1152 * 1024);
  float* hglob = (float*)(SMB + 1168 * 1024);        // 32 KB (2x4096 floats)
  unsigned* flags = (unsigned*)(SMB + 1216 * 1024);

  auto wat = [&](int l, int m, int hl) {
    return WATT + ((size_t)((l * 4 + m) * 2 + hl)) * 262144;
  };

  // fused weight split (single dispatch)
  {
    dim3 g(4096, 13);
    k_splitall<<<g, 256, 0, stream>>>(wq, wk, wv, wo, w1, w2, conv_w,
                                      WATT, W1T, W2T, CWT);
  }

  auto mg = [&](const u16* Ah, const u16* Al, const u16* Bh, const u16* Bl,
                const float* bias, float* C, int M, int N, int K) {
    dim3 g(N / 128, M / 128);
    k_mgemm<0, 0, 0><<<g, 256, 0, stream>>>(Ah, Al, Bh, Bl, bias, C, nullptr, nullptr,
                                            M, N, K, 0, nullptr, nullptr, nullptr, nullptr);
  };

  // ---------------- embed ----------------
  k_embed<<<BATCH * LL1, 256, 0, stream>>>(x, emb_w, emb_b, S0, P0, P1);

  // ---------------- encoder layer 1 (L=2048, u=40) ----------------
  {
    const int Lc = LL1, u = 40, M = BATCH * LL1;
    mg(P0, P1, wat(0, 0, 0), wat(0, 0, 1), bq, S1, M, 512, 512);
    mg(P0, P1, wat(0, 1, 0), wat(0, 1, 1), bk, S2, M, 512, 512);
    mg(P0, P1, wat(0, 2, 0), wat(0, 2, 1), bv, S3, M, 512, 512);
    k_qk_m<<<M, 320, 0, stream>>>(S1, S2, idx1, Mbuf, Lc, u);
    k_topk<<<64, 256, 0, stream>>>(Mbuf, mtop, Lc, u);
    k_colsum1<<<dim3(BATCH, 32), 512, 0, stream>>>(S3, csp, Lc, Lc / 32);
    k_colsum2<<<BATCH, 512, 0, stream>>>(csp, nullptr, vmh, vml, 32, 1.f / Lc);
    k_ctx_fillb<<<(BATCH * Lc * 128) / 256, 256, 0, stream>>>(P2, P3, vmh, vml, Lc);
    k_attn_mq<<<64 * 8, 256, 0, stream>>>(S1, S2, S3, mtop, P2, P3, Lc, u, 8);
    mg(P2, P3, wat(0, 3, 0), wat(0, 3, 1), bo, S1, M, 512, 512);
    k_add_ln<<<M, 256, 0, stream>>>(S0, S1, ln1g, ln1b, S2, P0, P1);
    u16* hidh = (u16*)S0;
    u16* hidl = (u16*)S1;
    for (int c = 0; c < 2; c++) {
      dim3 g1(16, 64);
      k_mgemm<1, 0, 1><<<g1, 256, 0, stream>>>(
          P0 + (size_t)c * 8192 * 512, P1 + (size_t)c * 8192 * 512,
          W1T, W1T + 1048576, b1, nullptr, hidh, hidl, 8192, 2048, 512, 0,
          nullptr, nullptr, nullptr, nullptr);
      dim3 g2(4, 64);
      k_mgemm<0, 0, 0><<<g2, 256, 0, stream>>>(
          hidh, hidl, W2T, W2T + 1048576, b2, S3 + (size_t)c * 8192 * 512,
          nullptr, nullptr, 8192, 512, 2048, 0, nullptr, nullptr, nullptr, nullptr);
    }
    k_add_ln<<<M, 256, 0, stream>>>(S2, S3, ln2g, ln2b, nullptr, P0, P1);
  }

  // ---------------- conv distill ----------------
  {
    dim3 g(4, 128);
    k_mgemm<2, 1, 0><<<g, 256, 0, stream>>>(P0, P1, CWT, CWT + 786432, conv_b,
                                            S1, nullptr, nullptr, 16384, 512, 1536,
                                            LL1, bn_m, bn_v, bn_g, bn_b);
    k_pool<<<(BATCH * LL2 * 512) / 256, 256, 0, stream>>>(S1, S2, P0, P1);
  }

  // ---------------- encoder layer 2 (L=1024, u=35) ----------------
  {
    const int Lc = LL2, u = 35, M = BATCH * LL2;
    float* Qb = S1;
    float* Kb = S1 + 4194304;
    float* Vb = S3;
    float* AOb = S3 + 4194304;
    mg(P0, P1, wat(1, 0, 0), wat(1, 0, 1), bq + 512, Qb, M, 512, 512);
    mg(P0, P1, wat(1, 1, 0), wat(1, 1, 1), bk + 512, Kb, M, 512, 512);
    mg(P0, P1, wat(1, 2, 0), wat(1, 2, 1), bv + 512, Vb, M, 512, 512);
    k_qk_m<<<M, 320, 0, stream>>>(Qb, Kb, idx2, Mbuf, Lc, u);
    k_topk<<<64, 256, 0, stream>>>(Mbuf, mtop, Lc, u);
    k_colsum1<<<dim3(BATCH, 32), 512, 0, stream>>>(Vb, csp, Lc, Lc / 32);
    k_colsum2<<<BATCH, 512, 0, stream>>>(csp, nullptr, vmh, vml, 32, 1.f / Lc);
    k_ctx_fillb<<<(BATCH * Lc * 128) / 256, 256, 0, stream>>>(P2, P3, vmh, vml, Lc);
    k_attn_mq<<<64 * 7, 256, 0, stream>>>(Qb, Kb, Vb, mtop, P2, P3, Lc, u, 7);
    mg(P2, P3, wat(1, 3, 0), wat(1, 3, 1), bo + 512, AOb, M, 512, 512);
    k_add_ln<<<M, 256, 0, stream>>>(S2, AOb, ln1g + 512, ln1b + 512, S0, P0, P1);
    u16* hidh = (u16*)S1;
    u16* hidl = (u16*)S3;
    {
      dim3 g1(16, 64);
      k_mgemm<1, 0, 1><<<g1, 256, 0, stream>>>(
          P0, P1, W1T + (size_t)2 * 1048576, W1T + (size_t)3 * 1048576, b1 + 2048,
          nullptr, hidh, hidl, 8192, 2048, 512, 0, nullptr, nullptr, nullptr, nullptr);
      dim3 g2(4, 64);
      k_mgemm<0, 0, 0><<<g2, 256, 0, stream>>>(
          hidh, hidl, W2T + (size_t)2 * 1048576, W2T + (size_t)3 * 1048576, b2 + 512,
          S2, nullptr, nullptr, 8192, 512, 2048, 0, nullptr, nullptr, nullptr, nullptr);
    }
    k_add_ln<<<M, 256, 0, stream>>>(S0, S2, ln2g + 512, ln2b + 512, S3, nullptr, nullptr);
  }

  // ---------------- mean -> LSTM -> output ----------------
  k_colsum1<<<dim3(BATCH, 32), 512, 0, stream>>>(S3, csp, LL2, LL2 / 32);
  k_colsum2<<<BATCH, 512, 0, stream>>>(csp, encb, nullptr, nullptr, 32, 1.f / LL2);
  k_gx<<<(BATCH * 2048) / 256, 256, 0, stream>>>(encb, lstm_wih, lstm_bih, gxb, flags);
  k_lstm3<<<64, 256, 0, stream>>>(gxb, lstm_whh, lstm_bhh, out_w, out_b, outp,
                                  hglob, flags);
}